// Round 2
// baseline (3742.179 us; speedup 1.0000x reference)
//
#include <hip/hip_runtime.h>
#include <cmath>

// Problem geometry (fixed by setup_inputs)
#define HH 160
#define WW 192
#define DD 160
#define WD (WW*DD)          // 30720
#define NPTS (HH*WW*DD)     // 4,915,200
#define PAD 4               // WIN=9 -> pad 4
#define INV_WSZ (1.0f/729.0f)
#define ADAM_B1 0.9f
#define ADAM_B2 0.999f
#define ADAM_LR 0.1f
#define ADAM_EPS 1e-8f

// ---------------- persistent device-global scratch ----------------
// d_ws proved too small (round 1: silent guard return). Module-scope
// __device__ globals are allocated at .so load (outside graph capture)
// and are legal scratch. ~450 MB total on a 288 GB device.
__device__ float g_flowA[3*NPTS];
__device__ float g_flowB[3*NPTS];
__device__ float g_m   [3*NPTS];
__device__ float g_v   [3*NPTS];
__device__ float g_vh  [3*NPTS];
__device__ float g_X   [3*NPTS];
__device__ float g_Y   [3*NPTS];
__device__ float g_I   [NPTS];
__device__ float g_uJ  [NPTS];
__device__ float g_Jv  [NPTS];
__device__ double g_part[2048];

// ---------------- helpers ----------------

__device__ __forceinline__ float fetchx(const float* __restrict__ x, int i, int j, int k) {
    if ((unsigned)i >= (unsigned)HH || (unsigned)j >= (unsigned)WW || (unsigned)k >= (unsigned)DD)
        return 0.0f;
    return x[(i*WW + j)*DD + k];
}

// ---------------- warp forward: I = trilinear(x, grid + flow) ----------------

__global__ void warp_fwd_k(const float* __restrict__ x, const float* __restrict__ finit,
                           int fin_code)
{
    int idx = blockIdx.x*blockDim.x + threadIdx.x;
    if (idx >= NPTS) return;
    const float* fin = (fin_code == 0) ? finit : ((fin_code == 1) ? g_flowA : g_flowB);
    int d = idx % DD;
    int w = (idx / DD) % WW;
    int h = idx / WD;
    float c0 = (float)h + fin[idx];
    float c1 = (float)w + fin[NPTS + idx];
    float c2 = (float)d + fin[2*NPTS + idx];
    float fl0 = floorf(c0), fl1 = floorf(c1), fl2 = floorf(c2);
    int i0 = (int)fl0, j0 = (int)fl1, k0 = (int)fl2;
    float fx = c0 - fl0, fy = c1 - fl1, fz = c2 - fl2;
    float v000 = fetchx(x, i0,   j0,   k0  ), v001 = fetchx(x, i0,   j0,   k0+1);
    float v010 = fetchx(x, i0,   j0+1, k0  ), v011 = fetchx(x, i0,   j0+1, k0+1);
    float v100 = fetchx(x, i0+1, j0,   k0  ), v101 = fetchx(x, i0+1, j0,   k0+1);
    float v110 = fetchx(x, i0+1, j0+1, k0  ), v111 = fetchx(x, i0+1, j0+1, k0+1);
    float c00 = v000*(1.0f-fz) + v001*fz;
    float c01 = v010*(1.0f-fz) + v011*fz;
    float c10 = v100*(1.0f-fz) + v101*fz;
    float c11 = v110*(1.0f-fz) + v111*fz;
    float a0 = c00*(1.0f-fy) + c01*fy;
    float a1 = c10*(1.0f-fy) + c11*fy;
    g_I[idx] = a0*(1.0f-fx) + a1*fx;
}

// ---------------- window-sum (box 9) separable passes ----------------
// AXIS: 0=H, 1=W. XY=true: g_X -> g_Y, else g_Y -> g_X. Fields field-major.
template<int NF, int AXIS, bool XY>
__global__ void box_pass_k()
{
    int idx = blockIdx.x*blockDim.x + threadIdx.x;
    if (idx >= NPTS) return;
    const float* in = XY ? g_X : g_Y;
    float* out      = XY ? g_Y : g_X;
    int d = idx % DD;
    int w = (idx / DD) % WW;
    int h = idx / WD;
    const int stride = (AXIS == 0) ? WD : ((AXIS == 1) ? DD : 1);
    const int coord  = (AXIS == 0) ? h  : ((AXIS == 1) ? w  : d);
    const int len    = (AXIS == 0) ? HH : ((AXIS == 1) ? WW : DD);
    int lo = (coord >= PAD) ? -PAD : -coord;
    int hi = (coord + PAD <= len - 1) ? PAD : (len - 1 - coord);
#pragma unroll
    for (int f = 0; f < NF; f++) {
        const float* p = in + f*NPTS + idx;
        float s = 0.0f;
        for (int k = lo; k <= hi; k++) s += p[k*stride];
        out[f*NPTS + idx] = s;
    }
}

// D-axis first pass for the moment fields, products on the fly:
// X0 = sum_d I, X1 = sum_d I*I, X2 = sum_d I*J
__global__ void momentsD_k(const float* __restrict__ J)
{
    int idx = blockIdx.x*blockDim.x + threadIdx.x;
    if (idx >= NPTS) return;
    int d = idx % DD;
    int lo = (d >= PAD) ? -PAD : -d;
    int hi = (d + PAD <= DD - 1) ? PAD : (DD - 1 - d);
    float s1 = 0.f, s2 = 0.f, s3 = 0.f;
    for (int k = lo; k <= hi; k++) {
        float a = g_I[idx + k];
        float b = J[idx + k];
        s1 += a; s2 += a*a; s3 += a*b;
    }
    g_X[idx] = s1; g_X[NPTS + idx] = s2; g_X[2*NPTS + idx] = s3;
}

// D-axis first pass for J stats: X0 = sum_d J, X1 = sum_d J*J
__global__ void jmomentsD_k(const float* __restrict__ J)
{
    int idx = blockIdx.x*blockDim.x + threadIdx.x;
    if (idx >= NPTS) return;
    int d = idx % DD;
    int lo = (d >= PAD) ? -PAD : -d;
    int hi = (d + PAD <= DD - 1) ? PAD : (DD - 1 - d);
    float s1 = 0.f, s2 = 0.f;
    for (int k = lo; k <= hi; k++) {
        float b = J[idx + k];
        s1 += b; s2 += b*b;
    }
    g_X[idx] = s1; g_X[NPTS + idx] = s2;
}

__global__ void jstats_k()
{
    int idx = blockIdx.x*blockDim.x + threadIdx.x;
    if (idx >= NPTS) return;
    float js = g_X[idx], j2s = g_X[NPTS + idx];
    float u = js * INV_WSZ;
    g_uJ[idx] = u;
    g_Jv[idx] = j2s - u*js;
}

// Per-voxel NCC adjoint fields: Y0 = A, Y1 = B, Y2 = A*u_J + 2*B*u_I
__global__ void fields_k()
{
    int idx = blockIdx.x*blockDim.x + threadIdx.x;
    if (idx >= NPTS) return;
    float Is  = g_X[idx];
    float I2s = g_X[NPTS + idx];
    float IJs = g_X[2*NPTS + idx];
    float uI = Is * INV_WSZ;
    float uj = g_uJ[idx];
    float jv = g_Jv[idx];
    float cross = IJs - uj*Is;
    float Ivar  = I2s - uI*Is;
    float den = Ivar*jv + 1e-5f;
    float invden = 1.0f / den;
    float A = 2.0f*cross*invden;
    float B = -cross*cross*jv*invden*invden;
    g_Y[idx]          = A;
    g_Y[NPTS + idx]   = B;
    g_Y[2*NPTS + idx] = A*uj + 2.0f*B*uI;
}

// ---------------- fused NCC-grad + warp-backward + reg-grad + Adam ----------------
__global__ void grad_adam_k(const float* __restrict__ x, const float* __restrict__ y,
                            const float* __restrict__ finit,
                            int fin_code, int fout_code,
                            float inv_bc1, float inv_sqrt_bc2, int is_first)
{
    int idx = blockIdx.x*blockDim.x + threadIdx.x;
    if (idx >= NPTS) return;
    const float* fin = (fin_code == 0) ? finit : ((fin_code == 1) ? g_flowA : g_flowB);
    float* fout = (fout_code == 1) ? g_flowA : g_flowB;
    int d = idx % DD;
    int w = (idx / DD) % WW;
    int h = idx / WD;

    // dL_ncc/dI(p) = -(1/N) [ J*boxA + 2 I*boxB - boxC ]   (boxed fields in g_X)
    float gI = -(1.0f/(float)NPTS) *
               (y[idx]*g_X[idx] + 2.0f*g_I[idx]*g_X[NPTS + idx] - g_X[2*NPTS + idx]);

    float f0 = fin[idx], f1 = fin[NPTS + idx], f2 = fin[2*NPTS + idx];
    float c0 = (float)h + f0, c1 = (float)w + f1, c2 = (float)d + f2;
    float fl0 = floorf(c0), fl1 = floorf(c1), fl2 = floorf(c2);
    int i0 = (int)fl0, j0 = (int)fl1, k0 = (int)fl2;
    float fx = c0 - fl0, fy = c1 - fl1, fz = c2 - fl2;
    float v000 = fetchx(x, i0,   j0,   k0  ), v001 = fetchx(x, i0,   j0,   k0+1);
    float v010 = fetchx(x, i0,   j0+1, k0  ), v011 = fetchx(x, i0,   j0+1, k0+1);
    float v100 = fetchx(x, i0+1, j0,   k0  ), v101 = fetchx(x, i0+1, j0,   k0+1);
    float v110 = fetchx(x, i0+1, j0+1, k0  ), v111 = fetchx(x, i0+1, j0+1, k0+1);

    float gx = (1.0f-fy)*((v100-v000)*(1.0f-fz) + (v101-v001)*fz)
             +        fy*((v110-v010)*(1.0f-fz) + (v111-v011)*fz);
    float gy = (1.0f-fx)*((v010-v000)*(1.0f-fz) + (v011-v001)*fz)
             +        fx*((v110-v100)*(1.0f-fz) + (v111-v101)*fz);
    float gz = (1.0f-fx)*((v001-v000)*(1.0f-fy) + (v011-v010)*fy)
             +        fx*((v101-v100)*(1.0f-fy) + (v111-v110)*fy);

    const float coefH = 2.0f / (3.0f * (float)(3*(HH-1)*WW*DD));
    const float coefW = 2.0f / (3.0f * (float)(3*HH*(WW-1)*DD));
    const float coefD = 2.0f / (3.0f * (float)(3*HH*WW*(DD-1)));

    float fv[3] = {f0, f1, f2};
    float gs[3] = {gI*gx, gI*gy, gI*gz};

#pragma unroll
    for (int c = 0; c < 3; c++) {
        int o = c*NPTS + idx;
        float fc = fv[c];
        float r = 0.0f;
        if (h > 0)      r += coefH*(fc - fin[o - WD]);
        if (h < HH-1)   r -= coefH*(fin[o + WD] - fc);
        if (w > 0)      r += coefW*(fc - fin[o - DD]);
        if (w < WW-1)   r -= coefW*(fin[o + DD] - fc);
        if (d > 0)      r += coefD*(fc - fin[o - 1]);
        if (d < DD-1)   r -= coefD*(fin[o + 1] - fc);
        float g = gs[c] + r;

        float mm, vv, vhh;
        if (is_first) { mm = 0.0f; vv = 0.0f; vhh = 0.0f; }
        else          { mm = g_m[o]; vv = g_v[o]; vhh = g_vh[o]; }
        mm  = ADAM_B1*mm + (1.0f - ADAM_B1)*g;
        vv  = ADAM_B2*vv + (1.0f - ADAM_B2)*g*g;
        vhh = fmaxf(vhh, vv);
        g_m[o] = mm; g_v[o] = vv; g_vh[o] = vhh;
        float den = sqrtf(vhh)*inv_sqrt_bc2 + ADAM_EPS;
        fout[o] = fc - ADAM_LR*(mm*inv_bc1)/den;
    }
}

// ---------------- final MSE(flow, initial_flow) ----------------

__global__ void mse_partial_k(const float* __restrict__ b)
{
    __shared__ double sd[256];
    int tid = threadIdx.x;
    double s = 0.0;
    for (int i = blockIdx.x*256 + tid; i < 3*NPTS; i += gridDim.x*256) {
        float df = g_flowA[i] - b[i];
        s += (double)df * (double)df;
    }
    sd[tid] = s; __syncthreads();
    for (int o = 128; o > 0; o >>= 1) {
        if (tid < o) sd[tid] += sd[tid + o];
        __syncthreads();
    }
    if (tid == 0) g_part[blockIdx.x] = sd[0];
}

__global__ void mse_final_k(int nblk, float* __restrict__ out)
{
    __shared__ double sd[256];
    int tid = threadIdx.x;
    double s = 0.0;
    for (int i = tid; i < nblk; i += 256) s += g_part[i];
    sd[tid] = s; __syncthreads();
    for (int o = 128; o > 0; o >>= 1) {
        if (tid < o) sd[tid] += sd[tid + o];
        __syncthreads();
    }
    if (tid == 0) out[0] = (float)(sd[0] / (3.0*(double)NPTS));
}

// ---------------- launch ----------------

extern "C" void kernel_launch(void* const* d_in, const int* in_sizes, int n_in,
                              void* d_out, int out_size, void* d_ws, size_t ws_size,
                              hipStream_t stream)
{
    const float* x    = (const float*)d_in[0];
    const float* y    = (const float*)d_in[1];
    const float* finit= (const float*)d_in[2];
    (void)d_ws; (void)ws_size;

    const int NB = 2048;
    dim3 blk(256);
    dim3 grd((NPTS + 255)/256);

    // J-side stats (flow-independent): box(J), box(J^2) -> u_J, J_var
    jmomentsD_k<<<grd, blk, 0, stream>>>(y);
    box_pass_k<2,1,true ><<<grd, blk, 0, stream>>>();   // X -> Y (W axis)
    box_pass_k<2,0,false><<<grd, blk, 0, stream>>>();   // Y -> X (H axis)
    jstats_k<<<grd, blk, 0, stream>>>();

    // fin/fout codes: 0 = finit, 1 = g_flowA, 2 = g_flowB
    int fin_code = 0;
    int fout_code = 1;
    for (int t = 1; t <= 5; t++) {
        warp_fwd_k<<<grd, blk, 0, stream>>>(x, finit, fin_code);
        momentsD_k<<<grd, blk, 0, stream>>>(y);              // -> X (D axis)
        box_pass_k<3,1,true ><<<grd, blk, 0, stream>>>();    // X -> Y (W)
        box_pass_k<3,0,false><<<grd, blk, 0, stream>>>();    // Y -> X (H)
        fields_k<<<grd, blk, 0, stream>>>();                 // X -> Y  (A,B,C)
        box_pass_k<3,2,false><<<grd, blk, 0, stream>>>();    // Y -> X (D)
        box_pass_k<3,1,true ><<<grd, blk, 0, stream>>>();    // X -> Y (W)
        box_pass_k<3,0,false><<<grd, blk, 0, stream>>>();    // Y -> X (H)
        double bc1 = 1.0 - pow(0.9, (double)t);
        double bc2 = 1.0 - pow(0.999, (double)t);
        grad_adam_k<<<grd, blk, 0, stream>>>(x, y, finit, fin_code, fout_code,
                                             (float)(1.0/bc1), (float)(1.0/sqrt(bc2)),
                                             (t == 1) ? 1 : 0);
        fin_code = fout_code;
        fout_code = (fout_code == 1) ? 2 : 1;
    }

    // after t=5 the latest flow is in g_flowA (A,B,A,B,A)
    mse_partial_k<<<NB, blk, 0, stream>>>(finit);
    mse_final_k<<<1, blk, 0, stream>>>(NB, (float*)d_out);
}

// Round 4
// 2582.115 us; speedup vs baseline: 1.4493x; 1.4493x over previous
//
#include <hip/hip_runtime.h>
#include <cmath>

// Problem geometry (fixed by setup_inputs)
#define HH 160
#define WW 192
#define DD 160
#define WD (WW*DD)          // 30720
#define NPTS (HH*WW*DD)     // 4,915,200
#define INV_WSZ (1.0f/729.0f)
#define ADAM_B1 0.9f
#define ADAM_B2 0.999f
#define ADAM_LR 0.1f
#define ADAM_EPS 1e-8f

// ---------------- persistent device-global scratch (~383 MB) ----------------
__device__ float g_flowA[3*NPTS];
__device__ float g_flowB[3*NPTS];
__device__ float g_m   [3*NPTS];
__device__ float g_v   [3*NPTS];
__device__ float g_vh  [3*NPTS];
__device__ float g_X   [3*NPTS];
__device__ float g_Y   [3*NPTS];
__device__ float g_uJ  [NPTS];
__device__ float g_Jv  [NPTS];
__device__ double g_part[2048];

// ---------------- helpers ----------------

__device__ __forceinline__ float fetchx(const float* __restrict__ x, int i, int j, int k) {
    if ((unsigned)i >= (unsigned)HH || (unsigned)j >= (unsigned)WW || (unsigned)k >= (unsigned)DD)
        return 0.0f;
    return x[(i*WW + j)*DD + k];
}

// ================= k1: fused warp + D-axis box of (I, I^2, I*J) =================
// One d-line (160) per threadIdx.y, 2 lines/block -> 320 threads (5 waves exact).
__global__ void warp_momD_k(const float* __restrict__ x, const float* __restrict__ y,
                            const float* __restrict__ finit, int fin_code)
{
    __shared__ float sI[2][DD];
    __shared__ float sJ[2][DD];
    int tx = threadIdx.x;                 // 0..159 = d
    int ty = threadIdx.y;                 // 0..1
    int line = blockIdx.x*2 + ty;         // h*WW + w
    int h = line / WW, w = line % WW;
    int idx = line*DD + tx;
    const float* fin = (fin_code == 0) ? finit : ((fin_code == 1) ? g_flowA : g_flowB);

    float c0 = (float)h + fin[idx];
    float c1 = (float)w + fin[NPTS + idx];
    float c2 = (float)tx + fin[2*NPTS + idx];
    float fl0 = floorf(c0), fl1 = floorf(c1), fl2 = floorf(c2);
    int i0 = (int)fl0, j0 = (int)fl1, k0 = (int)fl2;
    float fx = c0 - fl0, fy = c1 - fl1, fz = c2 - fl2;
    float v000 = fetchx(x, i0,   j0,   k0  ), v001 = fetchx(x, i0,   j0,   k0+1);
    float v010 = fetchx(x, i0,   j0+1, k0  ), v011 = fetchx(x, i0,   j0+1, k0+1);
    float v100 = fetchx(x, i0+1, j0,   k0  ), v101 = fetchx(x, i0+1, j0,   k0+1);
    float v110 = fetchx(x, i0+1, j0+1, k0  ), v111 = fetchx(x, i0+1, j0+1, k0+1);
    float c00 = v000*(1.0f-fz) + v001*fz;
    float c01 = v010*(1.0f-fz) + v011*fz;
    float c10 = v100*(1.0f-fz) + v101*fz;
    float c11 = v110*(1.0f-fz) + v111*fz;
    float a0 = c00*(1.0f-fy) + c01*fy;
    float a1 = c10*(1.0f-fy) + c11*fy;
    sI[ty][tx] = a0*(1.0f-fx) + a1*fx;
    sJ[ty][tx] = y[idx];
    __syncthreads();

    int lo = (tx < 4) ? -tx : -4;
    int hi = (tx > DD-5) ? (DD-1-tx) : 4;
    float s1 = 0.f, s2 = 0.f, s3 = 0.f;
    for (int k = lo; k <= hi; k++) {
        float a = sI[ty][tx+k], b = sJ[ty][tx+k];
        s1 += a; s2 += a*a; s3 += a*b;
    }
    g_X[idx] = s1; g_X[NPTS + idx] = s2; g_X[2*NPTS + idx] = s3;
}

// ================= k2/k4: W-axis box via LDS plane tile =================
// Tile: fixed h, full w (192), d-chunk 32. 1 global read + 9 LDS reads / element.
// Always g_X -> g_Y (both the moments chain and the fields chain are X->Y;
// round-3 bug was running the fields pass Y->X while grad_adam reads Y).
template<int NF>
__global__ void boxW_k()
{
    __shared__ float s[WW*32];
    const float* in = g_X;
    float* out      = g_Y;
    int h  = blockIdx.x;
    int d0 = blockIdx.y*32;
    int t  = threadIdx.x;
#pragma unroll
    for (int f = 0; f < NF; f++) {
        const float* base = in + f*NPTS + h*WD + d0;
        for (int e = t; e < WW*32; e += 256) {
            int wq = e >> 5, dd = e & 31;
            s[e] = base[wq*DD + dd];
        }
        __syncthreads();
        float* ob = out + f*NPTS + h*WD + d0;
        for (int e = t; e < WW*32; e += 256) {
            int wq = e >> 5, dd = e & 31;
            int lo = (wq < 4) ? -wq : -4;
            int hi = (wq > WW-5) ? (WW-1-wq) : 4;
            float sum = 0.f;
            for (int k = lo; k <= hi; k++) sum += s[e + k*32];
            ob[wq*DD + dd] = sum;
        }
        __syncthreads();
    }
}

// ================= k3: H-box(moments) + fields + H-box(fields), one kernel =================
// Tile: fixed w, full h (160), d-chunk 16. LDS 41 KB -> ~3 blocks/CU.
// Reads g_Y (D,W-boxed moments), writes g_X (H-boxed fields).
__global__ void boxH_fields_k()
{
    __shared__ float sa[HH*16];        // staging for one moment field
    __shared__ float sf[3][HH*16];     // H-boxed moments -> (in place) fields A,B,C
    int w  = blockIdx.x;
    int d0 = blockIdx.y*16;
    int t  = threadIdx.x;

    // Phase A: H-box each moment field
#pragma unroll
    for (int f = 0; f < 3; f++) {
        const float* base = g_Y + f*NPTS + w*DD + d0;
        for (int e = t; e < HH*16; e += 256) {
            int hh = e >> 4, dd = e & 15;
            sa[e] = base[hh*WD + dd];
        }
        __syncthreads();
        for (int e = t; e < HH*16; e += 256) {
            int hh = e >> 4;
            int lo = (hh < 4) ? -hh : -4;
            int hi = (hh > HH-5) ? (HH-1-hh) : 4;
            float sum = 0.f;
            for (int k = lo; k <= hi; k++) sum += sa[e + k*16];
            sf[f][e] = sum;
        }
        __syncthreads();
    }

    // Phase B: pointwise fields A,B,C from fully-boxed moments (in place)
    for (int e = t; e < HH*16; e += 256) {
        int hh = e >> 4, dd = e & 15;
        int idxg = hh*WD + w*DD + d0 + dd;
        float Is  = sf[0][e];
        float I2s = sf[1][e];
        float IJs = sf[2][e];
        float uI = Is * INV_WSZ;
        float uj = g_uJ[idxg];
        float jv = g_Jv[idxg];
        float cross = IJs - uj*Is;
        float Ivar  = I2s - uI*Is;
        float den = Ivar*jv + 1e-5f;
        float inv = 1.0f / den;
        float A = 2.0f*cross*inv;
        float B = -cross*cross*jv*inv*inv;
        sf[0][e] = A;
        sf[1][e] = B;
        sf[2][e] = A*uj + 2.0f*B*uI;
    }
    __syncthreads();

    // Phase C: H-box the fields -> g_X
#pragma unroll
    for (int f = 0; f < 3; f++) {
        float* ob = g_X + f*NPTS + w*DD + d0;
        for (int e = t; e < HH*16; e += 256) {
            int hh = e >> 4, dd = e & 15;
            int lo = (hh < 4) ? -hh : -4;
            int hi = (hh > HH-5) ? (HH-1-hh) : 4;
            float sum = 0.f;
            for (int k = lo; k <= hi; k++) sum += sf[f][e + k*16];
            ob[hh*WD + dd] = sum;
        }
    }
}

// ================= k5: inline D-box + warp recompute + reg + Adam =================
// Reads g_Y (H,W-boxed fields), D-boxes inline (contiguous taps, L1-resident).
__global__ void grad_adam_k(const float* __restrict__ x, const float* __restrict__ y,
                            const float* __restrict__ finit,
                            int fin_code, int fout_code,
                            float inv_bc1, float inv_sqrt_bc2, int is_first)
{
    int idx = blockIdx.x*blockDim.x + threadIdx.x;
    if (idx >= NPTS) return;
    const float* fin = (fin_code == 0) ? finit : ((fin_code == 1) ? g_flowA : g_flowB);
    float* fout = (fout_code == 1) ? g_flowA : g_flowB;
    int d = idx % DD;
    int w = (idx / DD) % WW;
    int h = idx / WD;

    int lo = (d < 4) ? -d : -4;
    int hi = (d > DD-5) ? (DD-1-d) : 4;
    float SA = 0.f, SB = 0.f, SC = 0.f;
    for (int k = lo; k <= hi; k++) {
        SA += g_Y[idx + k];
        SB += g_Y[NPTS + idx + k];
        SC += g_Y[2*NPTS + idx + k];
    }

    float f0 = fin[idx], f1 = fin[NPTS + idx], f2 = fin[2*NPTS + idx];
    float c0 = (float)h + f0, c1 = (float)w + f1, c2 = (float)d + f2;
    float fl0 = floorf(c0), fl1 = floorf(c1), fl2 = floorf(c2);
    int i0 = (int)fl0, j0 = (int)fl1, k0 = (int)fl2;
    float fx = c0 - fl0, fy = c1 - fl1, fz = c2 - fl2;
    float v000 = fetchx(x, i0,   j0,   k0  ), v001 = fetchx(x, i0,   j0,   k0+1);
    float v010 = fetchx(x, i0,   j0+1, k0  ), v011 = fetchx(x, i0,   j0+1, k0+1);
    float v100 = fetchx(x, i0+1, j0,   k0  ), v101 = fetchx(x, i0+1, j0,   k0+1);
    float v110 = fetchx(x, i0+1, j0+1, k0  ), v111 = fetchx(x, i0+1, j0+1, k0+1);

    // I recomputed from the corners (g_I eliminated)
    float c00 = v000*(1.0f-fz) + v001*fz;
    float c01 = v010*(1.0f-fz) + v011*fz;
    float c10 = v100*(1.0f-fz) + v101*fz;
    float c11 = v110*(1.0f-fz) + v111*fz;
    float a0 = c00*(1.0f-fy) + c01*fy;
    float a1 = c10*(1.0f-fy) + c11*fy;
    float Ival = a0*(1.0f-fx) + a1*fx;

    float gI = -(1.0f/(float)NPTS) * (y[idx]*SA + 2.0f*Ival*SB - SC);

    float gx = (1.0f-fy)*((v100-v000)*(1.0f-fz) + (v101-v001)*fz)
             +        fy*((v110-v010)*(1.0f-fz) + (v111-v011)*fz);
    float gy = (1.0f-fx)*((v010-v000)*(1.0f-fz) + (v011-v001)*fz)
             +        fx*((v110-v100)*(1.0f-fz) + (v111-v101)*fz);
    float gz = (1.0f-fx)*((v001-v000)*(1.0f-fy) + (v011-v010)*fy)
             +        fx*((v101-v100)*(1.0f-fy) + (v111-v110)*fy);

    const float coefH = 2.0f / (3.0f * (float)(3*(HH-1)*WW*DD));
    const float coefW = 2.0f / (3.0f * (float)(3*HH*(WW-1)*DD));
    const float coefD = 2.0f / (3.0f * (float)(3*HH*WW*(DD-1)));

    float fv[3] = {f0, f1, f2};
    float gs[3] = {gI*gx, gI*gy, gI*gz};

#pragma unroll
    for (int c = 0; c < 3; c++) {
        int o = c*NPTS + idx;
        float fc = fv[c];
        float r = 0.0f;
        if (h > 0)      r += coefH*(fc - fin[o - WD]);
        if (h < HH-1)   r -= coefH*(fin[o + WD] - fc);
        if (w > 0)      r += coefW*(fc - fin[o - DD]);
        if (w < WW-1)   r -= coefW*(fin[o + DD] - fc);
        if (d > 0)      r += coefD*(fc - fin[o - 1]);
        if (d < DD-1)   r -= coefD*(fin[o + 1] - fc);
        float g = gs[c] + r;

        float mm, vv, vhh;
        if (is_first) { mm = 0.0f; vv = 0.0f; vhh = 0.0f; }
        else          { mm = g_m[o]; vv = g_v[o]; vhh = g_vh[o]; }
        mm  = ADAM_B1*mm + (1.0f - ADAM_B1)*g;
        vv  = ADAM_B2*vv + (1.0f - ADAM_B2)*g*g;
        vhh = fmaxf(vhh, vv);
        g_m[o] = mm; g_v[o] = vv; g_vh[o] = vhh;
        float den = sqrtf(vhh)*inv_sqrt_bc2 + ADAM_EPS;
        fout[o] = fc - ADAM_LR*(mm*inv_bc1)/den;
    }
}

// ================= pre-loop J stats =================

__global__ void jmomD_k(const float* __restrict__ J)
{
    __shared__ float sJ[2][DD];
    int tx = threadIdx.x, ty = threadIdx.y;
    int line = blockIdx.x*2 + ty;
    int idx = line*DD + tx;
    sJ[ty][tx] = J[idx];
    __syncthreads();
    int lo = (tx < 4) ? -tx : -4;
    int hi = (tx > DD-5) ? (DD-1-tx) : 4;
    float s1 = 0.f, s2 = 0.f;
    for (int k = lo; k <= hi; k++) {
        float b = sJ[ty][tx+k];
        s1 += b; s2 += b*b;
    }
    g_X[idx] = s1; g_X[NPTS + idx] = s2;
}

__global__ void boxH2_jstats_k()
{
    int idx = blockIdx.x*blockDim.x + threadIdx.x;
    if (idx >= NPTS) return;
    int h = idx / WD;
    int lo = (h < 4) ? -h : -4;
    int hi = (h > HH-5) ? (HH-1-h) : 4;
    float s1 = 0.f, s2 = 0.f;
    for (int k = lo; k <= hi; k++) {
        s1 += g_Y[idx + k*WD];
        s2 += g_Y[NPTS + idx + k*WD];
    }
    float u = s1 * INV_WSZ;
    g_uJ[idx] = u;
    g_Jv[idx] = s2 - u*s1;
}

// ================= final MSE =================

__global__ void mse_partial_k(const float* __restrict__ b)
{
    __shared__ double sd[256];
    int tid = threadIdx.x;
    double s = 0.0;
    for (int i = blockIdx.x*256 + tid; i < 3*NPTS; i += gridDim.x*256) {
        float df = g_flowA[i] - b[i];
        s += (double)df * (double)df;
    }
    sd[tid] = s; __syncthreads();
    for (int o = 128; o > 0; o >>= 1) {
        if (tid < o) sd[tid] += sd[tid + o];
        __syncthreads();
    }
    if (tid == 0) g_part[blockIdx.x] = sd[0];
}

__global__ void mse_final_k(int nblk, float* __restrict__ out)
{
    __shared__ double sd[256];
    int tid = threadIdx.x;
    double s = 0.0;
    for (int i = tid; i < nblk; i += 256) s += g_part[i];
    sd[tid] = s; __syncthreads();
    for (int o = 128; o > 0; o >>= 1) {
        if (tid < o) sd[tid] += sd[tid + o];
        __syncthreads();
    }
    if (tid == 0) out[0] = (float)(sd[0] / (3.0*(double)NPTS));
}

// ================= launch =================

extern "C" void kernel_launch(void* const* d_in, const int* in_sizes, int n_in,
                              void* d_out, int out_size, void* d_ws, size_t ws_size,
                              hipStream_t stream)
{
    const float* x    = (const float*)d_in[0];
    const float* y    = (const float*)d_in[1];
    const float* finit= (const float*)d_in[2];
    (void)d_ws; (void)ws_size;

    const int NB = 2048;
    dim3 blk(256);
    dim3 grd((NPTS + 255)/256);
    dim3 lineBlk(DD, 2);
    dim3 lineGrd(HH*WW/2);
    dim3 wGrd(HH, DD/32);
    dim3 hGrd(WW, DD/16);

    // J-side stats (flow-independent)
    jmomD_k<<<lineGrd, lineBlk, 0, stream>>>(y);
    boxW_k<2><<<wGrd, blk, 0, stream>>>();             // X -> Y (W)
    boxH2_jstats_k<<<grd, blk, 0, stream>>>();         // Y -> uJ, Jv (H inline)

    // fin/fout codes: 0 = finit, 1 = g_flowA, 2 = g_flowB
    int fin_code = 0, fout_code = 1;
    for (int t = 1; t <= 5; t++) {
        warp_momD_k<<<lineGrd, lineBlk, 0, stream>>>(x, y, finit, fin_code);  // -> X (D-boxed moments)
        boxW_k<3><<<wGrd, blk, 0, stream>>>();                                // X -> Y (W)
        boxH_fields_k<<<hGrd, blk, 0, stream>>>();                            // Y -> X (H, fields, H)
        boxW_k<3><<<wGrd, blk, 0, stream>>>();                                // X -> Y (W)  [round-3 bug: was Y->X]
        double bc1 = 1.0 - pow(0.9, (double)t);
        double bc2 = 1.0 - pow(0.999, (double)t);
        grad_adam_k<<<grd, blk, 0, stream>>>(x, y, finit, fin_code, fout_code,
                                             (float)(1.0/bc1), (float)(1.0/sqrt(bc2)),
                                             (t == 1) ? 1 : 0);               // Y d-boxed inline
        fin_code = fout_code;
        fout_code = (fout_code == 1) ? 2 : 1;
    }

    // after t=5 the latest flow is in g_flowA (A,B,A,B,A)
    mse_partial_k<<<NB, blk, 0, stream>>>(finit);
    mse_final_k<<<1, blk, 0, stream>>>(NB, (float*)d_out);
}

// Round 5
// 2025.461 us; speedup vs baseline: 1.8476x; 1.2748x over previous
//
#include <hip/hip_runtime.h>
#include <cmath>

// Problem geometry (fixed by setup_inputs)
#define HH 160
#define WW 192
#define DD 160
#define WD (WW*DD)          // 30720
#define NPTS (HH*WW*DD)     // 4,915,200
#define NP4  (NPTS/4)
#define INV_WSZ (1.0f/729.0f)
#define ADAM_B1 0.9f
#define ADAM_B2 0.999f
#define ADAM_LR 0.1f
#define ADAM_EPS 1e-8f

// ---------------- persistent device-global scratch (~383 MB) ----------------
__device__ __align__(16) float g_flowA[3*NPTS];
__device__ __align__(16) float g_flowB[3*NPTS];
__device__ __align__(16) float g_m   [3*NPTS];
__device__ __align__(16) float g_v   [3*NPTS];
__device__ __align__(16) float g_vh  [3*NPTS];
__device__ __align__(16) float g_X   [3*NPTS];
__device__ __align__(16) float g_Y   [3*NPTS];
__device__ __align__(16) float g_uJ  [NPTS];
__device__ __align__(16) float g_Jv  [NPTS];
__device__ double g_part[2048];

// ---------------- helpers ----------------

__device__ __forceinline__ float4 ld4(const float* p) { return *reinterpret_cast<const float4*>(p); }
__device__ __forceinline__ void  st4(float* p, float4 v) { *reinterpret_cast<float4*>(p) = v; }
#define UNPK(V,A) { A[0]=(V).x; A[1]=(V).y; A[2]=(V).z; A[3]=(V).w; }

__device__ __forceinline__ float fetchx(const float* __restrict__ x, int i, int j, int k) {
    if ((unsigned)i >= (unsigned)HH || (unsigned)j >= (unsigned)WW || (unsigned)k >= (unsigned)DD)
        return 0.0f;
    return x[(i*WW + j)*DD + k];
}

// 12-float window [idx-4, idx+8) with zero-padding at line edges (fp-exact clip:
// adding 0.0f is identity; tap order preserved).
__device__ __forceinline__ void load12(const float* base, int idx, int dp, float* t) {
    float4 a = (dp == 0)    ? float4{0,0,0,0} : ld4(base + idx - 4);
    float4 b = ld4(base + idx);
    float4 c = (dp == DD-4) ? float4{0,0,0,0} : ld4(base + idx + 4);
    t[0]=a.x; t[1]=a.y; t[2]=a.z; t[3]=a.w;
    t[4]=b.x; t[5]=b.y; t[6]=b.z; t[7]=b.w;
    t[8]=c.x; t[9]=c.y; t[10]=c.z; t[11]=c.w;
}

// ================= k1: fused warp + D-axis box of (I, I^2, I*J) =================
// Block (40,8): 8 (h,w)-lines, each thread owns 4 consecutive d.
__global__ void __launch_bounds__(320) warp_momD_k(
        const float* __restrict__ x, const float* __restrict__ y,
        const float* __restrict__ finit, int fin_code)
{
    __shared__ __align__(16) float sI[8][168];   // 4 zero-pad front/back
    __shared__ __align__(16) float sJ[8][168];
    int tx = threadIdx.x;                 // 0..39
    int ty = threadIdx.y;                 // 0..7
    int line = blockIdx.x*8 + ty;         // h*WW + w
    int h = line / WW, w = line % WW;
    int dp = tx*4;
    int idx = line*DD + dp;
    const float* fin = (fin_code == 0) ? finit : ((fin_code == 1) ? g_flowA : g_flowB);

    float F0[4], F1[4], F2[4], Y4[4];
    { float4 a = ld4(fin + idx);          UNPK(a, F0); }
    { float4 a = ld4(fin + NPTS + idx);   UNPK(a, F1); }
    { float4 a = ld4(fin + 2*NPTS + idx); UNPK(a, F2); }
    { float4 a = ld4(y + idx);            UNPK(a, Y4); }

#pragma unroll
    for (int e = 0; e < 4; e++) {
        float c0 = (float)h + F0[e];
        float c1 = (float)w + F1[e];
        float c2 = (float)(dp + e) + F2[e];
        float fl0 = floorf(c0), fl1 = floorf(c1), fl2 = floorf(c2);
        int i0 = (int)fl0, j0 = (int)fl1, k0 = (int)fl2;
        float fx = c0 - fl0, fy = c1 - fl1, fz = c2 - fl2;
        float v000 = fetchx(x, i0,   j0,   k0  ), v001 = fetchx(x, i0,   j0,   k0+1);
        float v010 = fetchx(x, i0,   j0+1, k0  ), v011 = fetchx(x, i0,   j0+1, k0+1);
        float v100 = fetchx(x, i0+1, j0,   k0  ), v101 = fetchx(x, i0+1, j0,   k0+1);
        float v110 = fetchx(x, i0+1, j0+1, k0  ), v111 = fetchx(x, i0+1, j0+1, k0+1);
        float c00 = v000*(1.0f-fz) + v001*fz;
        float c01 = v010*(1.0f-fz) + v011*fz;
        float c10 = v100*(1.0f-fz) + v101*fz;
        float c11 = v110*(1.0f-fz) + v111*fz;
        float a0 = c00*(1.0f-fy) + c01*fy;
        float a1 = c10*(1.0f-fy) + c11*fy;
        sI[ty][4+dp+e] = a0*(1.0f-fx) + a1*fx;
        sJ[ty][4+dp+e] = Y4[e];
    }
    if (tx == 0) {
#pragma unroll
        for (int j = 0; j < 4; j++) { sI[ty][j] = 0.f; sJ[ty][j] = 0.f; }
    }
    if (tx == 39) {
#pragma unroll
        for (int j = 164; j < 168; j++) { sI[ty][j] = 0.f; sJ[ty][j] = 0.f; }
    }
    __syncthreads();

    float tI[12], tJ[12];
    { float4 a = ld4(&sI[ty][dp]);   UNPK(a, (&tI[0])); }
    { float4 a = ld4(&sI[ty][dp+4]); UNPK(a, (&tI[4])); }
    { float4 a = ld4(&sI[ty][dp+8]); UNPK(a, (&tI[8])); }
    { float4 a = ld4(&sJ[ty][dp]);   UNPK(a, (&tJ[0])); }
    { float4 a = ld4(&sJ[ty][dp+4]); UNPK(a, (&tJ[4])); }
    { float4 a = ld4(&sJ[ty][dp+8]); UNPK(a, (&tJ[8])); }

    float4 S1, S2, S3;
    float s1a[4], s2a[4], s3a[4];
#pragma unroll
    for (int e = 0; e < 4; e++) {
        float s1 = 0.f, s2 = 0.f, s3 = 0.f;
#pragma unroll
        for (int j = 0; j < 9; j++) {
            float a = tI[e+j], b = tJ[e+j];
            s1 += a; s2 += a*a; s3 += a*b;
        }
        s1a[e] = s1; s2a[e] = s2; s3a[e] = s3;
    }
    S1 = float4{s1a[0],s1a[1],s1a[2],s1a[3]};
    S2 = float4{s2a[0],s2a[1],s2a[2],s2a[3]};
    S3 = float4{s3a[0],s3a[1],s3a[2],s3a[3]};
    st4(g_X + idx, S1);
    st4(g_X + NPTS + idx, S2);
    st4(g_X + 2*NPTS + idx, S3);
}

// ================= k2/k4: W-axis box via LDS plane tile (g_X -> g_Y) =================
template<int NF>
__global__ void __launch_bounds__(256) boxW_k()
{
    __shared__ __align__(16) float s[WW][32];
    int h  = blockIdx.x;
    int d0 = blockIdx.y*32;
    int t  = threadIdx.x;
#pragma unroll
    for (int f = 0; f < NF; f++) {
        const float* base = g_X + f*NPTS + h*WD + d0;
        for (int q = t; q < WW*8; q += 256) {
            int wq = q >> 3, dq = (q & 7)*4;
            st4(&s[wq][dq], ld4(base + wq*DD + dq));
        }
        __syncthreads();
        float* ob = g_Y + f*NPTS + h*WD + d0;
        for (int q = t; q < WW*8; q += 256) {
            int wq = q >> 3, dq = (q & 7)*4;
            int lo = (wq < 4) ? -wq : -4;
            int hi = (wq > WW-5) ? (WW-1-wq) : 4;
            float4 acc = float4{0,0,0,0};
            for (int k = lo; k <= hi; k++) {
                float4 v = ld4(&s[wq+k][dq]);
                acc.x += v.x; acc.y += v.y; acc.z += v.z; acc.w += v.w;
            }
            st4(ob + wq*DD + dq, acc);
        }
        __syncthreads();
    }
}

// ================= k3: H-box(moments) + fields + H-box(fields) (g_Y -> g_X) =================
__global__ void __launch_bounds__(256) boxH_fields_k()
{
    __shared__ __align__(16) float sa[HH][16];
    __shared__ __align__(16) float sf[3][HH][16];
    int w  = blockIdx.x;
    int d0 = blockIdx.y*16;
    int t  = threadIdx.x;

    // Phase A: H-box each moment field
#pragma unroll
    for (int f = 0; f < 3; f++) {
        const float* base = g_Y + f*NPTS + w*DD + d0;
        for (int q = t; q < HH*4; q += 256) {
            int hh = q >> 2, dq = (q & 3)*4;
            st4(&sa[hh][dq], ld4(base + hh*WD + dq));
        }
        __syncthreads();
        for (int q = t; q < HH*4; q += 256) {
            int hh = q >> 2, dq = (q & 3)*4;
            int lo = (hh < 4) ? -hh : -4;
            int hi = (hh > HH-5) ? (HH-1-hh) : 4;
            float4 acc = float4{0,0,0,0};
            for (int k = lo; k <= hi; k++) {
                float4 v = ld4(&sa[hh+k][dq]);
                acc.x += v.x; acc.y += v.y; acc.z += v.z; acc.w += v.w;
            }
            st4(&sf[f][hh][dq], acc);
        }
        __syncthreads();
    }

    // Phase B: pointwise fields A,B,C (in place in sf)
    for (int q = t; q < HH*4; q += 256) {
        int hh = q >> 2, dq = (q & 3)*4;
        int idxg = hh*WD + w*DD + d0 + dq;
        float Is[4], I2s[4], IJs[4], UJ[4], JV[4];
        { float4 a = ld4(&sf[0][hh][dq]); UNPK(a, Is); }
        { float4 a = ld4(&sf[1][hh][dq]); UNPK(a, I2s); }
        { float4 a = ld4(&sf[2][hh][dq]); UNPK(a, IJs); }
        { float4 a = ld4(g_uJ + idxg);    UNPK(a, UJ); }
        { float4 a = ld4(g_Jv + idxg);    UNPK(a, JV); }
        float A_[4], B_[4], C_[4];
#pragma unroll
        for (int e = 0; e < 4; e++) {
            float uI = Is[e] * INV_WSZ;
            float cross = IJs[e] - UJ[e]*Is[e];
            float Ivar  = I2s[e] - uI*Is[e];
            float den = Ivar*JV[e] + 1e-5f;
            float inv = 1.0f / den;
            float A = 2.0f*cross*inv;
            float B = -cross*cross*JV[e]*inv*inv;
            A_[e] = A; B_[e] = B; C_[e] = A*UJ[e] + 2.0f*B*uI;
        }
        st4(&sf[0][hh][dq], float4{A_[0],A_[1],A_[2],A_[3]});
        st4(&sf[1][hh][dq], float4{B_[0],B_[1],B_[2],B_[3]});
        st4(&sf[2][hh][dq], float4{C_[0],C_[1],C_[2],C_[3]});
    }
    __syncthreads();

    // Phase C: H-box the fields -> g_X
#pragma unroll
    for (int f = 0; f < 3; f++) {
        float* ob = g_X + f*NPTS + w*DD + d0;
        for (int q = t; q < HH*4; q += 256) {
            int hh = q >> 2, dq = (q & 3)*4;
            int lo = (hh < 4) ? -hh : -4;
            int hi = (hh > HH-5) ? (HH-1-hh) : 4;
            float4 acc = float4{0,0,0,0};
            for (int k = lo; k <= hi; k++) {
                float4 v = ld4(&sf[f][hh+k][dq]);
                acc.x += v.x; acc.y += v.y; acc.z += v.z; acc.w += v.w;
            }
            st4(ob + hh*WD + dq, acc);
        }
    }
}

// NOTE after the W-box the fields chain ends in g_Y (X->Y), grad_adam reads g_Y.

// ================= k5: inline D-box + warp recompute + reg + Adam (vectorized) =================
__global__ void __launch_bounds__(256) grad_adam_k(
        const float* __restrict__ x, const float* __restrict__ y,
        const float* __restrict__ finit,
        int fin_code, int fout_code,
        float inv_bc1, float inv_sqrt_bc2, int is_first)
{
    int p = blockIdx.x*blockDim.x + threadIdx.x;   // pack of 4 voxels along d
    if (p >= NP4) return;
    int line = p / (DD/4);
    int dp   = (p % (DD/4))*4;
    int idx  = line*DD + dp;
    int w = line % WW;
    int h = line / WW;
    const float* fin = (fin_code == 0) ? finit : ((fin_code == 1) ? g_flowA : g_flowB);
    float* fout = (fout_code == 1) ? g_flowA : g_flowB;

    // ---- D-box of the H,W-boxed fields (12-float window, zero-padded) ----
    float SA[4], SB[4], SC[4];
    {
        float t[12];
        load12(g_Y,          idx, dp, t);
#pragma unroll
        for (int e = 0; e < 4; e++) { float s=0.f;
#pragma unroll
            for (int j = 0; j < 9; j++) s += t[e+j]; SA[e]=s; }
        load12(g_Y + NPTS,   idx, dp, t);
#pragma unroll
        for (int e = 0; e < 4; e++) { float s=0.f;
#pragma unroll
            for (int j = 0; j < 9; j++) s += t[e+j]; SB[e]=s; }
        load12(g_Y + 2*NPTS, idx, dp, t);
#pragma unroll
        for (int e = 0; e < 4; e++) { float s=0.f;
#pragma unroll
            for (int j = 0; j < 9; j++) s += t[e+j]; SC[e]=s; }
    }

    float F[3][4];
    { float4 a = ld4(fin + idx);          UNPK(a, F[0]); }
    { float4 a = ld4(fin + NPTS + idx);   UNPK(a, F[1]); }
    { float4 a = ld4(fin + 2*NPTS + idx); UNPK(a, F[2]); }
    float Y4[4];
    { float4 a = ld4(y + idx);            UNPK(a, Y4); }

    // ---- pass 1: per-element warp gather -> NCC flow-gradient GS[c][e] ----
    float GS[3][4];
#pragma unroll
    for (int e = 0; e < 4; e++) {
        int d = dp + e;
        float c0 = (float)h + F[0][e], c1 = (float)w + F[1][e], c2 = (float)d + F[2][e];
        float fl0 = floorf(c0), fl1 = floorf(c1), fl2 = floorf(c2);
        int i0 = (int)fl0, j0 = (int)fl1, k0 = (int)fl2;
        float fx = c0 - fl0, fy = c1 - fl1, fz = c2 - fl2;
        float v000 = fetchx(x, i0,   j0,   k0  ), v001 = fetchx(x, i0,   j0,   k0+1);
        float v010 = fetchx(x, i0,   j0+1, k0  ), v011 = fetchx(x, i0,   j0+1, k0+1);
        float v100 = fetchx(x, i0+1, j0,   k0  ), v101 = fetchx(x, i0+1, j0,   k0+1);
        float v110 = fetchx(x, i0+1, j0+1, k0  ), v111 = fetchx(x, i0+1, j0+1, k0+1);

        float c00 = v000*(1.0f-fz) + v001*fz;
        float c01 = v010*(1.0f-fz) + v011*fz;
        float c10 = v100*(1.0f-fz) + v101*fz;
        float c11 = v110*(1.0f-fz) + v111*fz;
        float a0 = c00*(1.0f-fy) + c01*fy;
        float a1 = c10*(1.0f-fy) + c11*fy;
        float Ival = a0*(1.0f-fx) + a1*fx;

        float gI = -(1.0f/(float)NPTS) * (Y4[e]*SA[e] + 2.0f*Ival*SB[e] - SC[e]);

        float gx = (1.0f-fy)*((v100-v000)*(1.0f-fz) + (v101-v001)*fz)
                 +        fy*((v110-v010)*(1.0f-fz) + (v111-v011)*fz);
        float gy = (1.0f-fx)*((v010-v000)*(1.0f-fz) + (v011-v001)*fz)
                 +        fx*((v110-v100)*(1.0f-fz) + (v111-v101)*fz);
        float gz = (1.0f-fx)*((v001-v000)*(1.0f-fy) + (v011-v010)*fy)
                 +        fx*((v101-v100)*(1.0f-fy) + (v111-v110)*fy);
        GS[0][e] = gI*gx; GS[1][e] = gI*gy; GS[2][e] = gI*gz;
    }

    const float coefH = 2.0f / (3.0f * (float)(3*(HH-1)*WW*DD));
    const float coefW = 2.0f / (3.0f * (float)(3*HH*(WW-1)*DD));
    const float coefD = 2.0f / (3.0f * (float)(3*HH*WW*(DD-1)));

    // ---- pass 2: per-component reg + Adam (bounded liveness) ----
#pragma unroll
    for (int c = 0; c < 3; c++) {
        const float* fc = fin + c*NPTS;
        int o = c*NPTS + idx;
        float FU[4], FD[4], FL[4], FR[4];
        { float4 a = (h > 0)    ? ld4(fc + idx - WD) : float4{0,0,0,0}; UNPK(a, FU); }
        { float4 a = (h < HH-1) ? ld4(fc + idx + WD) : float4{0,0,0,0}; UNPK(a, FD); }
        { float4 a = (w > 0)    ? ld4(fc + idx - DD) : float4{0,0,0,0}; UNPK(a, FL); }
        { float4 a = (w < WW-1) ? ld4(fc + idx + DD) : float4{0,0,0,0}; UNPK(a, FR); }
        float dl = (dp > 0)     ? fc[idx - 1] : 0.f;
        float dr = (dp < DD-4)  ? fc[idx + 4] : 0.f;

        float M[4], V[4], VH[4];
        if (is_first) {
#pragma unroll
            for (int e = 0; e < 4; e++) { M[e]=0.f; V[e]=0.f; VH[e]=0.f; }
        } else {
            { float4 a = ld4(g_m  + o); UNPK(a, M); }
            { float4 a = ld4(g_v  + o); UNPK(a, V); }
            { float4 a = ld4(g_vh + o); UNPK(a, VH); }
        }

        float O[4];
#pragma unroll
        for (int e = 0; e < 4; e++) {
            int d = dp + e;
            float f0 = F[c][e];
            float r = 0.0f;
            if (h > 0)     r += coefH*(f0 - FU[e]);
            if (h < HH-1)  r -= coefH*(FD[e] - f0);
            if (w > 0)     r += coefW*(f0 - FL[e]);
            if (w < WW-1)  r -= coefW*(FR[e] - f0);
            float left  = (e == 0) ? dl : F[c][e-1];
            float right = (e == 3) ? dr : F[c][e+1];
            if (d > 0)     r += coefD*(f0 - left);
            if (d < DD-1)  r -= coefD*(right - f0);
            float g = GS[c][e] + r;

            float mm  = ADAM_B1*M[e]  + (1.0f - ADAM_B1)*g;
            float vv  = ADAM_B2*V[e]  + (1.0f - ADAM_B2)*g*g;
            float vhh = fmaxf(VH[e], vv);
            M[e] = mm; V[e] = vv; VH[e] = vhh;
            float den = sqrtf(vhh)*inv_sqrt_bc2 + ADAM_EPS;
            O[e] = f0 - ADAM_LR*(mm*inv_bc1)/den;
        }
        st4(g_m  + o, float4{M[0],M[1],M[2],M[3]});
        st4(g_v  + o, float4{V[0],V[1],V[2],V[3]});
        st4(g_vh + o, float4{VH[0],VH[1],VH[2],VH[3]});
        st4(fout + o, float4{O[0],O[1],O[2],O[3]});
    }
}

// ================= pre-loop J stats =================

__global__ void jmomD_k(const float* __restrict__ J)
{
    __shared__ float sJ[2][DD];
    int tx = threadIdx.x, ty = threadIdx.y;
    int line = blockIdx.x*2 + ty;
    int idx = line*DD + tx;
    sJ[ty][tx] = J[idx];
    __syncthreads();
    int lo = (tx < 4) ? -tx : -4;
    int hi = (tx > DD-5) ? (DD-1-tx) : 4;
    float s1 = 0.f, s2 = 0.f;
    for (int k = lo; k <= hi; k++) {
        float b = sJ[ty][tx+k];
        s1 += b; s2 += b*b;
    }
    g_X[idx] = s1; g_X[NPTS + idx] = s2;
}

__global__ void __launch_bounds__(256) boxH2_jstats_k()
{
    int p = blockIdx.x*blockDim.x + threadIdx.x;
    if (p >= NP4) return;
    int idx = p*4;
    int h = idx / WD;
    int lo = (h < 4) ? -h : -4;
    int hi = (h > HH-5) ? (HH-1-h) : 4;
    float4 s1 = float4{0,0,0,0}, s2 = float4{0,0,0,0};
    for (int k = lo; k <= hi; k++) {
        float4 a = ld4(g_Y + idx + k*WD);
        float4 b = ld4(g_Y + NPTS + idx + k*WD);
        s1.x += a.x; s1.y += a.y; s1.z += a.z; s1.w += a.w;
        s2.x += b.x; s2.y += b.y; s2.z += b.z; s2.w += b.w;
    }
    float4 u  = float4{s1.x*INV_WSZ, s1.y*INV_WSZ, s1.z*INV_WSZ, s1.w*INV_WSZ};
    float4 jv = float4{s2.x - u.x*s1.x, s2.y - u.y*s1.y, s2.z - u.z*s1.z, s2.w - u.w*s1.w};
    st4(g_uJ + idx, u);
    st4(g_Jv + idx, jv);
}

// ================= final MSE =================

__global__ void mse_partial_k(const float* __restrict__ b)
{
    __shared__ double sd[256];
    int tid = threadIdx.x;
    double s = 0.0;
    for (int i = blockIdx.x*256 + tid; i < 3*NP4; i += gridDim.x*256) {
        float4 av = ld4(g_flowA + i*4);
        float4 bv = ld4(b + i*4);
        float d0 = av.x-bv.x, d1 = av.y-bv.y, d2 = av.z-bv.z, d3 = av.w-bv.w;
        s += (double)d0*(double)d0 + (double)d1*(double)d1
           + (double)d2*(double)d2 + (double)d3*(double)d3;
    }
    sd[tid] = s; __syncthreads();
    for (int o = 128; o > 0; o >>= 1) {
        if (tid < o) sd[tid] += sd[tid + o];
        __syncthreads();
    }
    if (tid == 0) g_part[blockIdx.x] = sd[0];
}

__global__ void mse_final_k(int nblk, float* __restrict__ out)
{
    __shared__ double sd[256];
    int tid = threadIdx.x;
    double s = 0.0;
    for (int i = tid; i < nblk; i += 256) s += g_part[i];
    sd[tid] = s; __syncthreads();
    for (int o = 128; o > 0; o >>= 1) {
        if (tid < o) sd[tid] += sd[tid + o];
        __syncthreads();
    }
    if (tid == 0) out[0] = (float)(sd[0] / (3.0*(double)NPTS));
}

// ================= launch =================

extern "C" void kernel_launch(void* const* d_in, const int* in_sizes, int n_in,
                              void* d_out, int out_size, void* d_ws, size_t ws_size,
                              hipStream_t stream)
{
    const float* x    = (const float*)d_in[0];
    const float* y    = (const float*)d_in[1];
    const float* finit= (const float*)d_in[2];
    (void)d_ws; (void)ws_size;

    const int NB = 2048;
    dim3 blk(256);
    dim3 grd4((NP4 + 255)/256);           // 4800 blocks, 4 voxels/thread
    dim3 lineBlk(DD, 2);
    dim3 lineGrd(HH*WW/2);
    dim3 wBlk(256);
    dim3 wGrd(HH, DD/32);
    dim3 hGrd(WW, DD/16);
    dim3 wmBlk(40, 8);
    dim3 wmGrd(HH*WW/8);

    // J-side stats (flow-independent)
    jmomD_k<<<lineGrd, lineBlk, 0, stream>>>(y);
    boxW_k<2><<<wGrd, wBlk, 0, stream>>>();            // X -> Y (W)
    boxH2_jstats_k<<<grd4, blk, 0, stream>>>();        // Y -> uJ, Jv (H inline)

    // fin/fout codes: 0 = finit, 1 = g_flowA, 2 = g_flowB
    int fin_code = 0, fout_code = 1;
    for (int t = 1; t <= 5; t++) {
        warp_momD_k<<<wmGrd, wmBlk, 0, stream>>>(x, y, finit, fin_code); // -> X (D-boxed moments)
        boxW_k<3><<<wGrd, wBlk, 0, stream>>>();                          // X -> Y (W)
        boxH_fields_k<<<hGrd, blk, 0, stream>>>();                       // Y -> X (H, fields, H)
        boxW_k<3><<<wGrd, wBlk, 0, stream>>>();                          // X -> Y (W)
        double bc1 = 1.0 - pow(0.9, (double)t);
        double bc2 = 1.0 - pow(0.999, (double)t);
        grad_adam_k<<<grd4, blk, 0, stream>>>(x, y, finit, fin_code, fout_code,
                                              (float)(1.0/bc1), (float)(1.0/sqrt(bc2)),
                                              (t == 1) ? 1 : 0);         // Y d-boxed inline
        fin_code = fout_code;
        fout_code = (fout_code == 1) ? 2 : 1;
    }

    // after t=5 the latest flow is in g_flowA (A,B,A,B,A)
    mse_partial_k<<<NB, blk, 0, stream>>>(finit);
    mse_final_k<<<1, blk, 0, stream>>>(NB, (float*)d_out);
}

// Round 6
// 1866.583 us; speedup vs baseline: 2.0048x; 1.0851x over previous
//
#include <hip/hip_runtime.h>
#include <cmath>

// Problem geometry (fixed by setup_inputs)
#define HH 160
#define WW 192
#define DD 160
#define WD (WW*DD)          // 30720
#define NPTS (HH*WW*DD)     // 4,915,200
#define NP4  (NPTS/4)
#define INV_WSZ (1.0f/729.0f)
#define ADAM_B1 0.9f
#define ADAM_B2 0.999f
#define ADAM_LR 0.1f
#define ADAM_EPS 1e-8f

// ---------------- persistent device-global scratch (~460 MB) ----------------
__device__ __align__(16) float g_flowA[3*NPTS];
__device__ __align__(16) float g_flowB[3*NPTS];
__device__ __align__(16) float g_m   [3*NPTS];
__device__ __align__(16) float g_v   [3*NPTS];
__device__ __align__(16) float g_vh  [3*NPTS];
__device__ __align__(16) float g_X   [3*NPTS];
__device__ __align__(16) float g_Y   [3*NPTS];
__device__ __align__(16) float g_I   [NPTS];     // trilinear value at fin
__device__ __align__(16) float g_G   [3*NPTS];   // trilinear coord-gradients at fin
__device__ __align__(16) float g_uJ  [NPTS];
__device__ __align__(16) float g_Jv  [NPTS];
__device__ double g_part[2048];

// ---------------- helpers ----------------

__device__ __forceinline__ float4 ld4(const float* p) { return *reinterpret_cast<const float4*>(p); }
__device__ __forceinline__ void  st4(float* p, float4 v) { *reinterpret_cast<float4*>(p) = v; }
#define UNPK(V,A) { A[0]=(V).x; A[1]=(V).y; A[2]=(V).z; A[3]=(V).w; }

__device__ __forceinline__ float fetchx(const float* __restrict__ x, int i, int j, int k) {
    if ((unsigned)i >= (unsigned)HH || (unsigned)j >= (unsigned)WW || (unsigned)k >= (unsigned)DD)
        return 0.0f;
    return x[(i*WW + j)*DD + k];
}

// 12-float window [idx-4, idx+8) with zero-padding at line edges (fp-exact clip).
__device__ __forceinline__ void load12(const float* base, int idx, int dp, float* t) {
    float4 a = (dp == 0)    ? float4{0,0,0,0} : ld4(base + idx - 4);
    float4 b = ld4(base + idx);
    float4 c = (dp == DD-4) ? float4{0,0,0,0} : ld4(base + idx + 4);
    t[0]=a.x; t[1]=a.y; t[2]=a.z; t[3]=a.w;
    t[4]=b.x; t[5]=b.y; t[6]=b.z; t[7]=b.w;
    t[8]=c.x; t[9]=c.y; t[10]=c.z; t[11]=c.w;
}

// ====== k1: fused warp + trilinear gradients + D-axis box of (I, I^2, I*J) ======
// Block (40,8): 8 (h,w)-lines, each thread owns 4 consecutive d.
// Also stores I (g_I) and gx,gy,gz (g_G) so grad_adam never gathers x.
__global__ void __launch_bounds__(320) warp_momD_k(
        const float* __restrict__ x, const float* __restrict__ y,
        const float* __restrict__ finit, int fin_code)
{
    __shared__ __align__(16) float sI[8][168];   // 4 zero-pad front/back
    __shared__ __align__(16) float sJ[8][168];
    int tx = threadIdx.x;                 // 0..39
    int ty = threadIdx.y;                 // 0..7
    int line = blockIdx.x*8 + ty;         // h*WW + w
    int h = line / WW, w = line % WW;
    int dp = tx*4;
    int idx = line*DD + dp;
    const float* fin = (fin_code == 0) ? finit : ((fin_code == 1) ? g_flowA : g_flowB);

    float F0[4], F1[4], F2[4], Y4[4];
    { float4 a = ld4(fin + idx);          UNPK(a, F0); }
    { float4 a = ld4(fin + NPTS + idx);   UNPK(a, F1); }
    { float4 a = ld4(fin + 2*NPTS + idx); UNPK(a, F2); }
    { float4 a = ld4(y + idx);            UNPK(a, Y4); }

    float GX[4], GY[4], GZ[4], IV[4];
#pragma unroll
    for (int e = 0; e < 4; e++) {
        float c0 = (float)h + F0[e];
        float c1 = (float)w + F1[e];
        float c2 = (float)(dp + e) + F2[e];
        float fl0 = floorf(c0), fl1 = floorf(c1), fl2 = floorf(c2);
        int i0 = (int)fl0, j0 = (int)fl1, k0 = (int)fl2;
        float fx = c0 - fl0, fy = c1 - fl1, fz = c2 - fl2;
        float v000 = fetchx(x, i0,   j0,   k0  ), v001 = fetchx(x, i0,   j0,   k0+1);
        float v010 = fetchx(x, i0,   j0+1, k0  ), v011 = fetchx(x, i0,   j0+1, k0+1);
        float v100 = fetchx(x, i0+1, j0,   k0  ), v101 = fetchx(x, i0+1, j0,   k0+1);
        float v110 = fetchx(x, i0+1, j0+1, k0  ), v111 = fetchx(x, i0+1, j0+1, k0+1);
        float c00 = v000*(1.0f-fz) + v001*fz;
        float c01 = v010*(1.0f-fz) + v011*fz;
        float c10 = v100*(1.0f-fz) + v101*fz;
        float c11 = v110*(1.0f-fz) + v111*fz;
        float a0 = c00*(1.0f-fy) + c01*fy;
        float a1 = c10*(1.0f-fy) + c11*fy;
        float Ival = a0*(1.0f-fx) + a1*fx;
        IV[e] = Ival;
        sI[ty][4+dp+e] = Ival;
        sJ[ty][4+dp+e] = Y4[e];
        GX[e] = (1.0f-fy)*((v100-v000)*(1.0f-fz) + (v101-v001)*fz)
              +        fy*((v110-v010)*(1.0f-fz) + (v111-v011)*fz);
        GY[e] = (1.0f-fx)*((v010-v000)*(1.0f-fz) + (v011-v001)*fz)
              +        fx*((v110-v100)*(1.0f-fz) + (v111-v101)*fz);
        GZ[e] = (1.0f-fx)*((v001-v000)*(1.0f-fy) + (v011-v010)*fy)
              +        fx*((v101-v100)*(1.0f-fy) + (v111-v110)*fy);
    }
    st4(g_I + idx,          float4{IV[0],IV[1],IV[2],IV[3]});
    st4(g_G + idx,          float4{GX[0],GX[1],GX[2],GX[3]});
    st4(g_G + NPTS + idx,   float4{GY[0],GY[1],GY[2],GY[3]});
    st4(g_G + 2*NPTS + idx, float4{GZ[0],GZ[1],GZ[2],GZ[3]});

    if (tx == 0) {
#pragma unroll
        for (int j = 0; j < 4; j++) { sI[ty][j] = 0.f; sJ[ty][j] = 0.f; }
    }
    if (tx == 39) {
#pragma unroll
        for (int j = 164; j < 168; j++) { sI[ty][j] = 0.f; sJ[ty][j] = 0.f; }
    }
    __syncthreads();

    float tI[12], tJ[12];
    { float4 a = ld4(&sI[ty][dp]);   UNPK(a, (&tI[0])); }
    { float4 a = ld4(&sI[ty][dp+4]); UNPK(a, (&tI[4])); }
    { float4 a = ld4(&sI[ty][dp+8]); UNPK(a, (&tI[8])); }
    { float4 a = ld4(&sJ[ty][dp]);   UNPK(a, (&tJ[0])); }
    { float4 a = ld4(&sJ[ty][dp+4]); UNPK(a, (&tJ[4])); }
    { float4 a = ld4(&sJ[ty][dp+8]); UNPK(a, (&tJ[8])); }

    float s1a[4], s2a[4], s3a[4];
#pragma unroll
    for (int e = 0; e < 4; e++) {
        float s1 = 0.f, s2 = 0.f, s3 = 0.f;
#pragma unroll
        for (int j = 0; j < 9; j++) {
            float a = tI[e+j], b = tJ[e+j];
            s1 += a; s2 += a*a; s3 += a*b;
        }
        s1a[e] = s1; s2a[e] = s2; s3a[e] = s3;
    }
    st4(g_X + idx,          float4{s1a[0],s1a[1],s1a[2],s1a[3]});
    st4(g_X + NPTS + idx,   float4{s2a[0],s2a[1],s2a[2],s2a[3]});
    st4(g_X + 2*NPTS + idx, float4{s3a[0],s3a[1],s3a[2],s3a[3]});
}

// ================= k2/k4: W-axis box via LDS plane tile (g_X -> g_Y) =================
template<int NF>
__global__ void __launch_bounds__(256) boxW_k()
{
    __shared__ __align__(16) float s[WW][32];
    int h  = blockIdx.x;
    int d0 = blockIdx.y*32;
    int t  = threadIdx.x;
#pragma unroll
    for (int f = 0; f < NF; f++) {
        const float* base = g_X + f*NPTS + h*WD + d0;
        for (int q = t; q < WW*8; q += 256) {
            int wq = q >> 3, dq = (q & 7)*4;
            st4(&s[wq][dq], ld4(base + wq*DD + dq));
        }
        __syncthreads();
        float* ob = g_Y + f*NPTS + h*WD + d0;
        for (int q = t; q < WW*8; q += 256) {
            int wq = q >> 3, dq = (q & 7)*4;
            int lo = (wq < 4) ? -wq : -4;
            int hi = (wq > WW-5) ? (WW-1-wq) : 4;
            float4 acc = float4{0,0,0,0};
            for (int k = lo; k <= hi; k++) {
                float4 v = ld4(&s[wq+k][dq]);
                acc.x += v.x; acc.y += v.y; acc.z += v.z; acc.w += v.w;
            }
            st4(ob + wq*DD + dq, acc);
        }
        __syncthreads();
    }
}

// ======= k3: H-box(moments) + fields + H-box(fields) (g_Y -> g_X), d-chunk 8 =======
// LDS 20.5 KB -> ~7 blocks/CU (was 41 KB / 3 blocks).
__global__ void __launch_bounds__(256) boxH_fields_k()
{
    __shared__ __align__(16) float sa[HH][8];
    __shared__ __align__(16) float sf[3][HH][8];
    int w  = blockIdx.x;
    int d0 = blockIdx.y*8;
    int t  = threadIdx.x;

    // Phase A: H-box each moment field
#pragma unroll
    for (int f = 0; f < 3; f++) {
        const float* base = g_Y + f*NPTS + w*DD + d0;
        for (int q = t; q < HH*2; q += 256) {
            int hh = q >> 1, dq = (q & 1)*4;
            st4(&sa[hh][dq], ld4(base + hh*WD + dq));
        }
        __syncthreads();
        for (int q = t; q < HH*2; q += 256) {
            int hh = q >> 1, dq = (q & 1)*4;
            int lo = (hh < 4) ? -hh : -4;
            int hi = (hh > HH-5) ? (HH-1-hh) : 4;
            float4 acc = float4{0,0,0,0};
            for (int k = lo; k <= hi; k++) {
                float4 v = ld4(&sa[hh+k][dq]);
                acc.x += v.x; acc.y += v.y; acc.z += v.z; acc.w += v.w;
            }
            st4(&sf[f][hh][dq], acc);
        }
        __syncthreads();
    }

    // Phase B: pointwise fields A,B,C (in place in sf)
    for (int q = t; q < HH*2; q += 256) {
        int hh = q >> 1, dq = (q & 1)*4;
        int idxg = hh*WD + w*DD + d0 + dq;
        float Is[4], I2s[4], IJs[4], UJ[4], JV[4];
        { float4 a = ld4(&sf[0][hh][dq]); UNPK(a, Is); }
        { float4 a = ld4(&sf[1][hh][dq]); UNPK(a, I2s); }
        { float4 a = ld4(&sf[2][hh][dq]); UNPK(a, IJs); }
        { float4 a = ld4(g_uJ + idxg);    UNPK(a, UJ); }
        { float4 a = ld4(g_Jv + idxg);    UNPK(a, JV); }
        float A_[4], B_[4], C_[4];
#pragma unroll
        for (int e = 0; e < 4; e++) {
            float uI = Is[e] * INV_WSZ;
            float cross = IJs[e] - UJ[e]*Is[e];
            float Ivar  = I2s[e] - uI*Is[e];
            float den = Ivar*JV[e] + 1e-5f;
            float inv = 1.0f / den;
            float A = 2.0f*cross*inv;
            float B = -cross*cross*JV[e]*inv*inv;
            A_[e] = A; B_[e] = B; C_[e] = A*UJ[e] + 2.0f*B*uI;
        }
        st4(&sf[0][hh][dq], float4{A_[0],A_[1],A_[2],A_[3]});
        st4(&sf[1][hh][dq], float4{B_[0],B_[1],B_[2],B_[3]});
        st4(&sf[2][hh][dq], float4{C_[0],C_[1],C_[2],C_[3]});
    }
    __syncthreads();

    // Phase C: H-box the fields -> g_X
#pragma unroll
    for (int f = 0; f < 3; f++) {
        float* ob = g_X + f*NPTS + w*DD + d0;
        for (int q = t; q < HH*2; q += 256) {
            int hh = q >> 1, dq = (q & 1)*4;
            int lo = (hh < 4) ? -hh : -4;
            int hi = (hh > HH-5) ? (HH-1-hh) : 4;
            float4 acc = float4{0,0,0,0};
            for (int k = lo; k <= hi; k++) {
                float4 v = ld4(&sf[f][hh+k][dq]);
                acc.x += v.x; acc.y += v.y; acc.z += v.z; acc.w += v.w;
            }
            st4(ob + hh*WD + dq, acc);
        }
    }
}

// ===== k5: inline D-box + (precomputed I, gx,gy,gz) + reg + Adam — no gather =====
__global__ void __launch_bounds__(256) grad_adam_k(
        const float* __restrict__ y,
        const float* __restrict__ finit,
        int fin_code, int fout_code,
        float inv_bc1, float inv_sqrt_bc2, int is_first)
{
    int p = blockIdx.x*blockDim.x + threadIdx.x;   // pack of 4 voxels along d
    if (p >= NP4) return;
    int line = p / (DD/4);
    int dp   = (p % (DD/4))*4;
    int idx  = line*DD + dp;
    int w = line % WW;
    int h = line / WW;
    const float* fin = (fin_code == 0) ? finit : ((fin_code == 1) ? g_flowA : g_flowB);
    float* fout = (fout_code == 1) ? g_flowA : g_flowB;

    // ---- D-box of the H,W-boxed fields (12-float window, zero-padded) ----
    float SA[4], SB[4], SC[4];
    {
        float t[12];
        load12(g_Y,          idx, dp, t);
#pragma unroll
        for (int e = 0; e < 4; e++) { float s=0.f;
#pragma unroll
            for (int j = 0; j < 9; j++) s += t[e+j]; SA[e]=s; }
        load12(g_Y + NPTS,   idx, dp, t);
#pragma unroll
        for (int e = 0; e < 4; e++) { float s=0.f;
#pragma unroll
            for (int j = 0; j < 9; j++) s += t[e+j]; SB[e]=s; }
        load12(g_Y + 2*NPTS, idx, dp, t);
#pragma unroll
        for (int e = 0; e < 4; e++) { float s=0.f;
#pragma unroll
            for (int j = 0; j < 9; j++) s += t[e+j]; SC[e]=s; }
    }

    float F[3][4];
    { float4 a = ld4(fin + idx);          UNPK(a, F[0]); }
    { float4 a = ld4(fin + NPTS + idx);   UNPK(a, F[1]); }
    { float4 a = ld4(fin + 2*NPTS + idx); UNPK(a, F[2]); }
    float Y4[4], I4[4], GX[4], GY[4], GZ[4];
    { float4 a = ld4(y + idx);            UNPK(a, Y4); }
    { float4 a = ld4(g_I + idx);          UNPK(a, I4); }
    { float4 a = ld4(g_G + idx);          UNPK(a, GX); }
    { float4 a = ld4(g_G + NPTS + idx);   UNPK(a, GY); }
    { float4 a = ld4(g_G + 2*NPTS + idx); UNPK(a, GZ); }

    float GS[3][4];
#pragma unroll
    for (int e = 0; e < 4; e++) {
        float gI = -(1.0f/(float)NPTS) * (Y4[e]*SA[e] + 2.0f*I4[e]*SB[e] - SC[e]);
        GS[0][e] = gI*GX[e]; GS[1][e] = gI*GY[e]; GS[2][e] = gI*GZ[e];
    }

    const float coefH = 2.0f / (3.0f * (float)(3*(HH-1)*WW*DD));
    const float coefW = 2.0f / (3.0f * (float)(3*HH*(WW-1)*DD));
    const float coefD = 2.0f / (3.0f * (float)(3*HH*WW*(DD-1)));

#pragma unroll
    for (int c = 0; c < 3; c++) {
        const float* fc = fin + c*NPTS;
        int o = c*NPTS + idx;
        float FU[4], FD[4], FL[4], FR[4];
        { float4 a = (h > 0)    ? ld4(fc + idx - WD) : float4{0,0,0,0}; UNPK(a, FU); }
        { float4 a = (h < HH-1) ? ld4(fc + idx + WD) : float4{0,0,0,0}; UNPK(a, FD); }
        { float4 a = (w > 0)    ? ld4(fc + idx - DD) : float4{0,0,0,0}; UNPK(a, FL); }
        { float4 a = (w < WW-1) ? ld4(fc + idx + DD) : float4{0,0,0,0}; UNPK(a, FR); }
        float dl = (dp > 0)     ? fc[idx - 1] : 0.f;
        float dr = (dp < DD-4)  ? fc[idx + 4] : 0.f;

        float M[4], V[4], VH[4];
        if (is_first) {
#pragma unroll
            for (int e = 0; e < 4; e++) { M[e]=0.f; V[e]=0.f; VH[e]=0.f; }
        } else {
            { float4 a = ld4(g_m  + o); UNPK(a, M); }
            { float4 a = ld4(g_v  + o); UNPK(a, V); }
            { float4 a = ld4(g_vh + o); UNPK(a, VH); }
        }

        float O[4];
#pragma unroll
        for (int e = 0; e < 4; e++) {
            int d = dp + e;
            float f0 = F[c][e];
            float r = 0.0f;
            if (h > 0)     r += coefH*(f0 - FU[e]);
            if (h < HH-1)  r -= coefH*(FD[e] - f0);
            if (w > 0)     r += coefW*(f0 - FL[e]);
            if (w < WW-1)  r -= coefW*(FR[e] - f0);
            float left  = (e == 0) ? dl : F[c][e-1];
            float right = (e == 3) ? dr : F[c][e+1];
            if (d > 0)     r += coefD*(f0 - left);
            if (d < DD-1)  r -= coefD*(right - f0);
            float g = GS[c][e] + r;

            float mm  = ADAM_B1*M[e]  + (1.0f - ADAM_B1)*g;
            float vv  = ADAM_B2*V[e]  + (1.0f - ADAM_B2)*g*g;
            float vhh = fmaxf(VH[e], vv);
            M[e] = mm; V[e] = vv; VH[e] = vhh;
            float den = sqrtf(vhh)*inv_sqrt_bc2 + ADAM_EPS;
            O[e] = f0 - ADAM_LR*(mm*inv_bc1)/den;
        }
        st4(g_m  + o, float4{M[0],M[1],M[2],M[3]});
        st4(g_v  + o, float4{V[0],V[1],V[2],V[3]});
        st4(g_vh + o, float4{VH[0],VH[1],VH[2],VH[3]});
        st4(fout + o, float4{O[0],O[1],O[2],O[3]});
    }
}

// ================= pre-loop J stats =================

__global__ void jmomD_k(const float* __restrict__ J)
{
    __shared__ float sJ[2][DD];
    int tx = threadIdx.x, ty = threadIdx.y;
    int line = blockIdx.x*2 + ty;
    int idx = line*DD + tx;
    sJ[ty][tx] = J[idx];
    __syncthreads();
    int lo = (tx < 4) ? -tx : -4;
    int hi = (tx > DD-5) ? (DD-1-tx) : 4;
    float s1 = 0.f, s2 = 0.f;
    for (int k = lo; k <= hi; k++) {
        float b = sJ[ty][tx+k];
        s1 += b; s2 += b*b;
    }
    g_X[idx] = s1; g_X[NPTS + idx] = s2;
}

__global__ void __launch_bounds__(256) boxH2_jstats_k()
{
    int p = blockIdx.x*blockDim.x + threadIdx.x;
    if (p >= NP4) return;
    int idx = p*4;
    int h = idx / WD;
    int lo = (h < 4) ? -h : -4;
    int hi = (h > HH-5) ? (HH-1-h) : 4;
    float4 s1 = float4{0,0,0,0}, s2 = float4{0,0,0,0};
    for (int k = lo; k <= hi; k++) {
        float4 a = ld4(g_Y + idx + k*WD);
        float4 b = ld4(g_Y + NPTS + idx + k*WD);
        s1.x += a.x; s1.y += a.y; s1.z += a.z; s1.w += a.w;
        s2.x += b.x; s2.y += b.y; s2.z += b.z; s2.w += b.w;
    }
    float4 u  = float4{s1.x*INV_WSZ, s1.y*INV_WSZ, s1.z*INV_WSZ, s1.w*INV_WSZ};
    float4 jv = float4{s2.x - u.x*s1.x, s2.y - u.y*s1.y, s2.z - u.z*s1.z, s2.w - u.w*s1.w};
    st4(g_uJ + idx, u);
    st4(g_Jv + idx, jv);
}

// ================= final MSE =================

__global__ void mse_partial_k(const float* __restrict__ b)
{
    __shared__ double sd[256];
    int tid = threadIdx.x;
    double s = 0.0;
    for (int i = blockIdx.x*256 + tid; i < 3*NP4; i += gridDim.x*256) {
        float4 av = ld4(g_flowA + i*4);
        float4 bv = ld4(b + i*4);
        float d0 = av.x-bv.x, d1 = av.y-bv.y, d2 = av.z-bv.z, d3 = av.w-bv.w;
        s += (double)d0*(double)d0 + (double)d1*(double)d1
           + (double)d2*(double)d2 + (double)d3*(double)d3;
    }
    sd[tid] = s; __syncthreads();
    for (int o = 128; o > 0; o >>= 1) {
        if (tid < o) sd[tid] += sd[tid + o];
        __syncthreads();
    }
    if (tid == 0) g_part[blockIdx.x] = sd[0];
}

__global__ void mse_final_k(int nblk, float* __restrict__ out)
{
    __shared__ double sd[256];
    int tid = threadIdx.x;
    double s = 0.0;
    for (int i = tid; i < nblk; i += 256) s += g_part[i];
    sd[tid] = s; __syncthreads();
    for (int o = 128; o > 0; o >>= 1) {
        if (tid < o) sd[tid] += sd[tid + o];
        __syncthreads();
    }
    if (tid == 0) out[0] = (float)(sd[0] / (3.0*(double)NPTS));
}

// ================= launch =================

extern "C" void kernel_launch(void* const* d_in, const int* in_sizes, int n_in,
                              void* d_out, int out_size, void* d_ws, size_t ws_size,
                              hipStream_t stream)
{
    const float* x    = (const float*)d_in[0];
    const float* y    = (const float*)d_in[1];
    const float* finit= (const float*)d_in[2];
    (void)d_ws; (void)ws_size;

    const int NB = 2048;
    dim3 blk(256);
    dim3 grd4((NP4 + 255)/256);
    dim3 lineBlk(DD, 2);
    dim3 lineGrd(HH*WW/2);
    dim3 wBlk(256);
    dim3 wGrd(HH, DD/32);
    dim3 hGrd(WW, DD/8);
    dim3 wmBlk(40, 8);
    dim3 wmGrd(HH*WW/8);

    // J-side stats (flow-independent)
    jmomD_k<<<lineGrd, lineBlk, 0, stream>>>(y);
    boxW_k<2><<<wGrd, wBlk, 0, stream>>>();            // X -> Y (W)
    boxH2_jstats_k<<<grd4, blk, 0, stream>>>();        // Y -> uJ, Jv (H inline)

    // fin/fout codes: 0 = finit, 1 = g_flowA, 2 = g_flowB
    int fin_code = 0, fout_code = 1;
    for (int t = 1; t <= 5; t++) {
        warp_momD_k<<<wmGrd, wmBlk, 0, stream>>>(x, y, finit, fin_code); // -> X, g_I, g_G
        boxW_k<3><<<wGrd, wBlk, 0, stream>>>();                          // X -> Y (W)
        boxH_fields_k<<<hGrd, blk, 0, stream>>>();                       // Y -> X (H, fields, H)
        boxW_k<3><<<wGrd, wBlk, 0, stream>>>();                          // X -> Y (W)
        double bc1 = 1.0 - pow(0.9, (double)t);
        double bc2 = 1.0 - pow(0.999, (double)t);
        grad_adam_k<<<grd4, blk, 0, stream>>>(y, finit, fin_code, fout_code,
                                              (float)(1.0/bc1), (float)(1.0/sqrt(bc2)),
                                              (t == 1) ? 1 : 0);         // Y d-boxed inline
        fin_code = fout_code;
        fout_code = (fout_code == 1) ? 2 : 1;
    }

    // after t=5 the latest flow is in g_flowA (A,B,A,B,A)
    mse_partial_k<<<NB, blk, 0, stream>>>(finit);
    mse_final_k<<<1, blk, 0, stream>>>(NB, (float*)d_out);
}

// Round 8
// 1799.279 us; speedup vs baseline: 2.0798x; 1.0374x over previous
//
#include <hip/hip_runtime.h>
#include <cmath>

// Problem geometry (fixed by setup_inputs)
#define HH 160
#define WW 192
#define DD 160
#define WD (WW*DD)          // 30720
#define NPTS (HH*WW*DD)     // 4,915,200
#define NP4  (NPTS/4)
#define INV_WSZ (1.0f/729.0f)
#define ADAM_B1 0.9f
#define ADAM_B2 0.999f
#define ADAM_LR 0.1f
#define ADAM_EPS 1e-8f
#define NBLK_FINAL 4800     // NP4/256 exactly

// ---------------- persistent device-global scratch (~460 MB) ----------------
__device__ __align__(16) float g_flowA[3*NPTS];
__device__ __align__(16) float g_flowB[3*NPTS];
__device__ __align__(16) float g_m   [3*NPTS];
__device__ __align__(16) float g_v   [3*NPTS];
__device__ __align__(16) float g_vh  [3*NPTS];
__device__ __align__(16) float g_X   [3*NPTS];
__device__ __align__(16) float g_Y   [3*NPTS];
__device__ __align__(16) float g_I   [NPTS];     // trilinear value at fin
__device__ __align__(16) float g_G   [3*NPTS];   // trilinear coord-gradients at fin
__device__ __align__(16) float g_uJ  [NPTS];
__device__ __align__(16) float g_Jv  [NPTS];
__device__ double g_part[8192];

// ---------------- helpers ----------------

typedef float nat4 __attribute__((ext_vector_type(4)));  // native clang vector for NT builtins

__device__ __forceinline__ float4 ld4(const float* p) { return *reinterpret_cast<const float4*>(p); }
__device__ __forceinline__ void  st4(float* p, float4 v) { *reinterpret_cast<float4*>(p) = v; }
__device__ __forceinline__ float4 ld4nt(const float* p) {
    nat4 t = __builtin_nontemporal_load(reinterpret_cast<const nat4*>(p));
    return float4{t.x, t.y, t.z, t.w};
}
__device__ __forceinline__ void st4nt(float* p, float4 v) {
    nat4 t = {v.x, v.y, v.z, v.w};
    __builtin_nontemporal_store(t, reinterpret_cast<nat4*>(p));
}
#define UNPK(V,A) { A[0]=(V).x; A[1]=(V).y; A[2]=(V).z; A[3]=(V).w; }

__device__ __forceinline__ float fetchx(const float* __restrict__ x, int i, int j, int k) {
    if ((unsigned)i >= (unsigned)HH || (unsigned)j >= (unsigned)WW || (unsigned)k >= (unsigned)DD)
        return 0.0f;
    return x[(i*WW + j)*DD + k];
}

// 12-float window [idx-4, idx+8) with zero-padding at line edges (fp-exact clip).
__device__ __forceinline__ void load12(const float* base, int idx, int dp, float* t) {
    float4 a = (dp == 0)    ? float4{0,0,0,0} : ld4(base + idx - 4);
    float4 b = ld4(base + idx);
    float4 c = (dp == DD-4) ? float4{0,0,0,0} : ld4(base + idx + 4);
    t[0]=a.x; t[1]=a.y; t[2]=a.z; t[3]=a.w;
    t[4]=b.x; t[5]=b.y; t[6]=b.z; t[7]=b.w;
    t[8]=c.x; t[9]=c.y; t[10]=c.z; t[11]=c.w;
}

// ====== k1: fused warp + trilinear gradients + D-axis box of (I, I^2, I*J) ======
__global__ void __launch_bounds__(320) warp_momD_k(
        const float* __restrict__ x, const float* __restrict__ y,
        const float* __restrict__ finit, int fin_code)
{
    __shared__ __align__(16) float sI[8][168];   // 4 zero-pad front/back
    __shared__ __align__(16) float sJ[8][168];
    int tx = threadIdx.x;                 // 0..39
    int ty = threadIdx.y;                 // 0..7
    int line = blockIdx.x*8 + ty;         // h*WW + w
    int h = line / WW, w = line % WW;
    int dp = tx*4;
    int idx = line*DD + dp;
    const float* fin = (fin_code == 0) ? finit : ((fin_code == 1) ? g_flowA : g_flowB);

    float F0[4], F1[4], F2[4], Y4[4];
    { float4 a = ld4(fin + idx);          UNPK(a, F0); }
    { float4 a = ld4(fin + NPTS + idx);   UNPK(a, F1); }
    { float4 a = ld4(fin + 2*NPTS + idx); UNPK(a, F2); }
    { float4 a = ld4(y + idx);            UNPK(a, Y4); }

    float GX[4], GY[4], GZ[4], IV[4];
#pragma unroll
    for (int e = 0; e < 4; e++) {
        float c0 = (float)h + F0[e];
        float c1 = (float)w + F1[e];
        float c2 = (float)(dp + e) + F2[e];
        float fl0 = floorf(c0), fl1 = floorf(c1), fl2 = floorf(c2);
        int i0 = (int)fl0, j0 = (int)fl1, k0 = (int)fl2;
        float fx = c0 - fl0, fy = c1 - fl1, fz = c2 - fl2;
        float v000 = fetchx(x, i0,   j0,   k0  ), v001 = fetchx(x, i0,   j0,   k0+1);
        float v010 = fetchx(x, i0,   j0+1, k0  ), v011 = fetchx(x, i0,   j0+1, k0+1);
        float v100 = fetchx(x, i0+1, j0,   k0  ), v101 = fetchx(x, i0+1, j0,   k0+1);
        float v110 = fetchx(x, i0+1, j0+1, k0  ), v111 = fetchx(x, i0+1, j0+1, k0+1);
        float c00 = v000*(1.0f-fz) + v001*fz;
        float c01 = v010*(1.0f-fz) + v011*fz;
        float c10 = v100*(1.0f-fz) + v101*fz;
        float c11 = v110*(1.0f-fz) + v111*fz;
        float a0 = c00*(1.0f-fy) + c01*fy;
        float a1 = c10*(1.0f-fy) + c11*fy;
        float Ival = a0*(1.0f-fx) + a1*fx;
        IV[e] = Ival;
        sI[ty][4+dp+e] = Ival;
        sJ[ty][4+dp+e] = Y4[e];
        GX[e] = (1.0f-fy)*((v100-v000)*(1.0f-fz) + (v101-v001)*fz)
              +        fy*((v110-v010)*(1.0f-fz) + (v111-v011)*fz);
        GY[e] = (1.0f-fx)*((v010-v000)*(1.0f-fz) + (v011-v001)*fz)
              +        fx*((v110-v100)*(1.0f-fz) + (v111-v101)*fz);
        GZ[e] = (1.0f-fx)*((v001-v000)*(1.0f-fy) + (v011-v010)*fy)
              +        fx*((v101-v100)*(1.0f-fy) + (v111-v110)*fy);
    }
    st4nt(g_I + idx,          float4{IV[0],IV[1],IV[2],IV[3]});
    st4nt(g_G + idx,          float4{GX[0],GX[1],GX[2],GX[3]});
    st4nt(g_G + NPTS + idx,   float4{GY[0],GY[1],GY[2],GY[3]});
    st4nt(g_G + 2*NPTS + idx, float4{GZ[0],GZ[1],GZ[2],GZ[3]});

    if (tx == 0) {
#pragma unroll
        for (int j = 0; j < 4; j++) { sI[ty][j] = 0.f; sJ[ty][j] = 0.f; }
    }
    if (tx == 39) {
#pragma unroll
        for (int j = 164; j < 168; j++) { sI[ty][j] = 0.f; sJ[ty][j] = 0.f; }
    }
    __syncthreads();

    float tI[12], tJ[12];
    { float4 a = ld4(&sI[ty][dp]);   UNPK(a, (&tI[0])); }
    { float4 a = ld4(&sI[ty][dp+4]); UNPK(a, (&tI[4])); }
    { float4 a = ld4(&sI[ty][dp+8]); UNPK(a, (&tI[8])); }
    { float4 a = ld4(&sJ[ty][dp]);   UNPK(a, (&tJ[0])); }
    { float4 a = ld4(&sJ[ty][dp+4]); UNPK(a, (&tJ[4])); }
    { float4 a = ld4(&sJ[ty][dp+8]); UNPK(a, (&tJ[8])); }

    float s1a[4], s2a[4], s3a[4];
#pragma unroll
    for (int e = 0; e < 4; e++) {
        float s1 = 0.f, s2 = 0.f, s3 = 0.f;
#pragma unroll
        for (int j = 0; j < 9; j++) {
            float a = tI[e+j], b = tJ[e+j];
            s1 += a; s2 += a*a; s3 += a*b;
        }
        s1a[e] = s1; s2a[e] = s2; s3a[e] = s3;
    }
    st4nt(g_X + idx,          float4{s1a[0],s1a[1],s1a[2],s1a[3]});
    st4nt(g_X + NPTS + idx,   float4{s2a[0],s2a[1],s2a[2],s2a[3]});
    st4nt(g_X + 2*NPTS + idx, float4{s3a[0],s3a[1],s3a[2],s3a[3]});
}

// ================= k2/k4: W-axis box via LDS plane tile (g_X -> g_Y) =================
template<int NF>
__global__ void __launch_bounds__(256) boxW_k()
{
    __shared__ __align__(16) float s[WW][32];
    int h  = blockIdx.x;
    int d0 = blockIdx.y*32;
    int t  = threadIdx.x;
#pragma unroll
    for (int f = 0; f < NF; f++) {
        const float* base = g_X + f*NPTS + h*WD + d0;
        for (int q = t; q < WW*8; q += 256) {
            int wq = q >> 3, dq = (q & 7)*4;
            st4(&s[wq][dq], ld4nt(base + wq*DD + dq));
        }
        __syncthreads();
        float* ob = g_Y + f*NPTS + h*WD + d0;
        for (int q = t; q < WW*8; q += 256) {
            int wq = q >> 3, dq = (q & 7)*4;
            int lo = (wq < 4) ? -wq : -4;
            int hi = (wq > WW-5) ? (WW-1-wq) : 4;
            float4 acc = float4{0,0,0,0};
            for (int k = lo; k <= hi; k++) {
                float4 v = ld4(&s[wq+k][dq]);
                acc.x += v.x; acc.y += v.y; acc.z += v.z; acc.w += v.w;
            }
            st4nt(ob + wq*DD + dq, acc);
        }
        __syncthreads();
    }
}

// ======= k3: H-box(moments) + fields + H-box(fields) (g_Y -> g_X) =======
// d-chunk 16 (64 B per H-line: full sector use). No staging buffer — the 9
// H-taps read global directly; per-field column (10 KB) is L1-resident.
// LDS 30.7 KB -> 5 blocks/CU.
__global__ void __launch_bounds__(256) boxH_fields_k()
{
    __shared__ __align__(16) float sf[3][HH][16];
    int w  = blockIdx.x;
    int d0 = blockIdx.y*16;
    int t  = threadIdx.x;

    // Phase A: H-box each moment field straight from global (L1 reuse on taps)
#pragma unroll
    for (int f = 0; f < 3; f++) {
        const float* base = g_Y + f*NPTS + w*DD + d0;
        for (int q = t; q < HH*4; q += 256) {
            int hh = q >> 2, dq = (q & 3)*4;
            int lo = (hh < 4) ? -hh : -4;
            int hi = (hh > HH-5) ? (HH-1-hh) : 4;
            float4 acc = float4{0,0,0,0};
            for (int k = lo; k <= hi; k++) {
                float4 v = ld4(base + (hh+k)*WD + dq);
                acc.x += v.x; acc.y += v.y; acc.z += v.z; acc.w += v.w;
            }
            st4(&sf[f][hh][dq], acc);
        }
    }
    __syncthreads();

    // Phase B: pointwise fields A,B,C — compute all, sync, then overwrite
    {
        float A_[2][4], B_[2][4], C_[2][4];
        int qi = 0;
        for (int q = t; q < HH*4; q += 256, qi++) {
            int hh = q >> 2, dq = (q & 3)*4;
            int idxg = hh*WD + w*DD + d0 + dq;
            float Is[4], I2s[4], IJs[4], UJ[4], JV[4];
            { float4 a = ld4(&sf[0][hh][dq]); UNPK(a, Is); }
            { float4 a = ld4(&sf[1][hh][dq]); UNPK(a, I2s); }
            { float4 a = ld4(&sf[2][hh][dq]); UNPK(a, IJs); }
            { float4 a = ld4(g_uJ + idxg);    UNPK(a, UJ); }
            { float4 a = ld4(g_Jv + idxg);    UNPK(a, JV); }
#pragma unroll
            for (int e = 0; e < 4; e++) {
                float uI = Is[e] * INV_WSZ;
                float cross = IJs[e] - UJ[e]*Is[e];
                float Ivar  = I2s[e] - uI*Is[e];
                float den = Ivar*JV[e] + 1e-5f;
                float inv = 1.0f / den;
                float A = 2.0f*cross*inv;
                float B = -cross*cross*JV[e]*inv*inv;
                A_[qi][e] = A; B_[qi][e] = B; C_[qi][e] = A*UJ[e] + 2.0f*B*uI;
            }
        }
        __syncthreads();
        qi = 0;
        for (int q = t; q < HH*4; q += 256, qi++) {
            int hh = q >> 2, dq = (q & 3)*4;
            st4(&sf[0][hh][dq], float4{A_[qi][0],A_[qi][1],A_[qi][2],A_[qi][3]});
            st4(&sf[1][hh][dq], float4{B_[qi][0],B_[qi][1],B_[qi][2],B_[qi][3]});
            st4(&sf[2][hh][dq], float4{C_[qi][0],C_[qi][1],C_[qi][2],C_[qi][3]});
        }
    }
    __syncthreads();

    // Phase C: H-box the fields -> g_X
#pragma unroll
    for (int f = 0; f < 3; f++) {
        float* ob = g_X + f*NPTS + w*DD + d0;
        for (int q = t; q < HH*4; q += 256) {
            int hh = q >> 2, dq = (q & 3)*4;
            int lo = (hh < 4) ? -hh : -4;
            int hi = (hh > HH-5) ? (HH-1-hh) : 4;
            float4 acc = float4{0,0,0,0};
            for (int k = lo; k <= hi; k++) {
                float4 v = ld4(&sf[f][hh+k][dq]);
                acc.x += v.x; acc.y += v.y; acc.z += v.z; acc.w += v.w;
            }
            st4nt(ob + hh*WD + dq, acc);
        }
    }
}

// ===== k5: inline D-box + (precomputed I, gx,gy,gz) + reg + Adam =====
// FINAL=true (t=5): m/v/vh/fout stores are dead; fuse MSE((flow_new - finit)^2)
// as per-block double partials instead.
template<bool FINAL>
__global__ void __launch_bounds__(256) grad_adam_k(
        const float* __restrict__ y,
        const float* __restrict__ finit,
        int fin_code, int fout_code,
        float inv_bc1, float inv_sqrt_bc2, int is_first)
{
    __shared__ double sd[256];
    int p = blockIdx.x*blockDim.x + threadIdx.x;   // pack of 4 voxels along d
    if (p >= NP4) return;
    int line = p / (DD/4);
    int dp   = (p % (DD/4))*4;
    int idx  = line*DD + dp;
    int w = line % WW;
    int h = line / WW;
    const float* fin = (fin_code == 0) ? finit : ((fin_code == 1) ? g_flowA : g_flowB);
    float* fout = (fout_code == 1) ? g_flowA : g_flowB;

    // ---- D-box of the H,W-boxed fields (12-float window, zero-padded) ----
    float SA[4], SB[4], SC[4];
    {
        float t[12];
        load12(g_Y,          idx, dp, t);
#pragma unroll
        for (int e = 0; e < 4; e++) { float s=0.f;
#pragma unroll
            for (int j = 0; j < 9; j++) s += t[e+j]; SA[e]=s; }
        load12(g_Y + NPTS,   idx, dp, t);
#pragma unroll
        for (int e = 0; e < 4; e++) { float s=0.f;
#pragma unroll
            for (int j = 0; j < 9; j++) s += t[e+j]; SB[e]=s; }
        load12(g_Y + 2*NPTS, idx, dp, t);
#pragma unroll
        for (int e = 0; e < 4; e++) { float s=0.f;
#pragma unroll
            for (int j = 0; j < 9; j++) s += t[e+j]; SC[e]=s; }
    }

    float F[3][4];
    { float4 a = ld4(fin + idx);          UNPK(a, F[0]); }
    { float4 a = ld4(fin + NPTS + idx);   UNPK(a, F[1]); }
    { float4 a = ld4(fin + 2*NPTS + idx); UNPK(a, F[2]); }
    float Y4[4], I4[4], GX[4], GY[4], GZ[4];
    { float4 a = ld4(y + idx);              UNPK(a, Y4); }
    { float4 a = ld4nt(g_I + idx);          UNPK(a, I4); }
    { float4 a = ld4nt(g_G + idx);          UNPK(a, GX); }
    { float4 a = ld4nt(g_G + NPTS + idx);   UNPK(a, GY); }
    { float4 a = ld4nt(g_G + 2*NPTS + idx); UNPK(a, GZ); }

    float GS[3][4];
#pragma unroll
    for (int e = 0; e < 4; e++) {
        float gI = -(1.0f/(float)NPTS) * (Y4[e]*SA[e] + 2.0f*I4[e]*SB[e] - SC[e]);
        GS[0][e] = gI*GX[e]; GS[1][e] = gI*GY[e]; GS[2][e] = gI*GZ[e];
    }

    const float coefH = 2.0f / (3.0f * (float)(3*(HH-1)*WW*DD));
    const float coefW = 2.0f / (3.0f * (float)(3*HH*(WW-1)*DD));
    const float coefD = 2.0f / (3.0f * (float)(3*HH*WW*(DD-1)));

    double msea = 0.0;

#pragma unroll
    for (int c = 0; c < 3; c++) {
        const float* fc = fin + c*NPTS;
        int o = c*NPTS + idx;
        float FU[4], FD[4], FL[4], FR[4];
        { float4 a = (h > 0)    ? ld4(fc + idx - WD) : float4{0,0,0,0}; UNPK(a, FU); }
        { float4 a = (h < HH-1) ? ld4(fc + idx + WD) : float4{0,0,0,0}; UNPK(a, FD); }
        { float4 a = (w > 0)    ? ld4(fc + idx - DD) : float4{0,0,0,0}; UNPK(a, FL); }
        { float4 a = (w < WW-1) ? ld4(fc + idx + DD) : float4{0,0,0,0}; UNPK(a, FR); }
        float dl = (dp > 0)     ? fc[idx - 1] : 0.f;
        float dr = (dp < DD-4)  ? fc[idx + 4] : 0.f;

        float M[4], V[4], VH[4];
        if (is_first) {
#pragma unroll
            for (int e = 0; e < 4; e++) { M[e]=0.f; V[e]=0.f; VH[e]=0.f; }
        } else {
            { float4 a = ld4nt(g_m  + o); UNPK(a, M); }
            { float4 a = ld4nt(g_v  + o); UNPK(a, V); }
            { float4 a = ld4nt(g_vh + o); UNPK(a, VH); }
        }

        float FI[4];
        if (FINAL) { float4 a = ld4(finit + o); UNPK(a, FI); }

        float O[4];
#pragma unroll
        for (int e = 0; e < 4; e++) {
            int d = dp + e;
            float f0 = F[c][e];
            float r = 0.0f;
            if (h > 0)     r += coefH*(f0 - FU[e]);
            if (h < HH-1)  r -= coefH*(FD[e] - f0);
            if (w > 0)     r += coefW*(f0 - FL[e]);
            if (w < WW-1)  r -= coefW*(FR[e] - f0);
            float left  = (e == 0) ? dl : F[c][e-1];
            float right = (e == 3) ? dr : F[c][e+1];
            if (d > 0)     r += coefD*(f0 - left);
            if (d < DD-1)  r -= coefD*(right - f0);
            float g = GS[c][e] + r;

            float mm  = ADAM_B1*M[e]  + (1.0f - ADAM_B1)*g;
            float vv  = ADAM_B2*V[e]  + (1.0f - ADAM_B2)*g*g;
            float vhh = fmaxf(VH[e], vv);
            M[e] = mm; V[e] = vv; VH[e] = vhh;
            float den = sqrtf(vhh)*inv_sqrt_bc2 + ADAM_EPS;
            O[e] = f0 - ADAM_LR*(mm*inv_bc1)/den;
            if (FINAL) {
                float df = O[e] - FI[e];
                msea += (double)df * (double)df;
            }
        }
        if (!FINAL) {
            st4nt(g_m  + o, float4{M[0],M[1],M[2],M[3]});
            st4nt(g_v  + o, float4{V[0],V[1],V[2],V[3]});
            st4nt(g_vh + o, float4{VH[0],VH[1],VH[2],VH[3]});
            st4(fout + o, float4{O[0],O[1],O[2],O[3]});
        }
    }

    if (FINAL) {
        int tid = threadIdx.x;
        sd[tid] = msea; __syncthreads();
        for (int o2 = 128; o2 > 0; o2 >>= 1) {
            if (tid < o2) sd[tid] += sd[tid + o2];
            __syncthreads();
        }
        if (tid == 0) g_part[blockIdx.x] = sd[0];
    }
}

// ================= pre-loop J stats =================

__global__ void jmomD_k(const float* __restrict__ J)
{
    __shared__ float sJ[2][DD];
    int tx = threadIdx.x, ty = threadIdx.y;
    int line = blockIdx.x*2 + ty;
    int idx = line*DD + tx;
    sJ[ty][tx] = J[idx];
    __syncthreads();
    int lo = (tx < 4) ? -tx : -4;
    int hi = (tx > DD-5) ? (DD-1-tx) : 4;
    float s1 = 0.f, s2 = 0.f;
    for (int k = lo; k <= hi; k++) {
        float b = sJ[ty][tx+k];
        s1 += b; s2 += b*b;
    }
    g_X[idx] = s1; g_X[NPTS + idx] = s2;
}

__global__ void __launch_bounds__(256) boxH2_jstats_k()
{
    int p = blockIdx.x*blockDim.x + threadIdx.x;
    if (p >= NP4) return;
    int idx = p*4;
    int h = idx / WD;
    int lo = (h < 4) ? -h : -4;
    int hi = (h > HH-5) ? (HH-1-h) : 4;
    float4 s1 = float4{0,0,0,0}, s2 = float4{0,0,0,0};
    for (int k = lo; k <= hi; k++) {
        float4 a = ld4(g_Y + idx + k*WD);
        float4 b = ld4(g_Y + NPTS + idx + k*WD);
        s1.x += a.x; s1.y += a.y; s1.z += a.z; s1.w += a.w;
        s2.x += b.x; s2.y += b.y; s2.z += b.z; s2.w += b.w;
    }
    float4 u  = float4{s1.x*INV_WSZ, s1.y*INV_WSZ, s1.z*INV_WSZ, s1.w*INV_WSZ};
    float4 jv = float4{s2.x - u.x*s1.x, s2.y - u.y*s1.y, s2.z - u.z*s1.z, s2.w - u.w*s1.w};
    st4(g_uJ + idx, u);
    st4(g_Jv + idx, jv);
}

// ================= final MSE fold =================

__global__ void mse_final_k(int nblk, float* __restrict__ out)
{
    __shared__ double sd[256];
    int tid = threadIdx.x;
    double s = 0.0;
    for (int i = tid; i < nblk; i += 256) s += g_part[i];
    sd[tid] = s; __syncthreads();
    for (int o = 128; o > 0; o >>= 1) {
        if (tid < o) sd[tid] += sd[tid + o];
        __syncthreads();
    }
    if (tid == 0) out[0] = (float)(sd[0] / (3.0*(double)NPTS));
}

// ================= launch =================

extern "C" void kernel_launch(void* const* d_in, const int* in_sizes, int n_in,
                              void* d_out, int out_size, void* d_ws, size_t ws_size,
                              hipStream_t stream)
{
    const float* x    = (const float*)d_in[0];
    const float* y    = (const float*)d_in[1];
    const float* finit= (const float*)d_in[2];
    (void)d_ws; (void)ws_size;

    dim3 blk(256);
    dim3 grd4((NP4 + 255)/256);           // 4800 blocks exactly
    dim3 lineBlk(DD, 2);
    dim3 lineGrd(HH*WW/2);
    dim3 wBlk(256);
    dim3 wGrd(HH, DD/32);
    dim3 hGrd(WW, DD/16);
    dim3 wmBlk(40, 8);
    dim3 wmGrd(HH*WW/8);

    // J-side stats (flow-independent)
    jmomD_k<<<lineGrd, lineBlk, 0, stream>>>(y);
    boxW_k<2><<<wGrd, wBlk, 0, stream>>>();            // X -> Y (W)
    boxH2_jstats_k<<<grd4, blk, 0, stream>>>();        // Y -> uJ, Jv (H inline)

    // fin/fout codes: 0 = finit, 1 = g_flowA, 2 = g_flowB
    int fin_code = 0, fout_code = 1;
    for (int t = 1; t <= 5; t++) {
        warp_momD_k<<<wmGrd, wmBlk, 0, stream>>>(x, y, finit, fin_code); // -> X, g_I, g_G
        boxW_k<3><<<wGrd, wBlk, 0, stream>>>();                          // X -> Y (W)
        boxH_fields_k<<<hGrd, blk, 0, stream>>>();                       // Y -> X (H, fields, H)
        boxW_k<3><<<wGrd, wBlk, 0, stream>>>();                          // X -> Y (W)
        double bc1 = 1.0 - pow(0.9, (double)t);
        double bc2 = 1.0 - pow(0.999, (double)t);
        if (t < 5) {
            grad_adam_k<false><<<grd4, blk, 0, stream>>>(y, finit, fin_code, fout_code,
                                                         (float)(1.0/bc1), (float)(1.0/sqrt(bc2)),
                                                         (t == 1) ? 1 : 0);
        } else {
            grad_adam_k<true><<<grd4, blk, 0, stream>>>(y, finit, fin_code, fout_code,
                                                        (float)(1.0/bc1), (float)(1.0/sqrt(bc2)), 0);
        }
        fin_code = fout_code;
        fout_code = (fout_code == 1) ? 2 : 1;
    }

    mse_final_k<<<1, blk, 0, stream>>>(NBLK_FINAL, (float*)d_out);
}